// Round 1
// baseline (16039.207 us; speedup 1.0000x reference)
//
#include <hip/hip_runtime.h>

// SDMamba forward. All GEMMs on MFMA f16 (fp32 accumulate); conv/scan/LN fp32 math.
// T = B*N = 27584 tokens. d_model=512, d_inner=1024.

typedef _Float16 f16;
typedef _Float16 f16x8 __attribute__((ext_vector_type(8)));
typedef _Float16 f16x4 __attribute__((ext_vector_type(4)));
typedef float    f32x4 __attribute__((ext_vector_type(4)));

constexpr int Bb  = 32;
constexpr int Lh  = 96;
constexpr int FUTc= 96;
constexpr int Nn  = 862;
constexpr int Dm  = 512;
constexpr int Ds  = 16;
constexpr int Di  = 1024;
constexpr int DRr = 32;
constexpr int TT  = Bb * Nn;     // 27584
constexpr float EPSf = 1e-5f;

__device__ __forceinline__ float sigm(float x){ return 1.f / (1.f + __expf(-x)); }

// async global->LDS, 16B per lane. dest = wave-uniform base (+ lane*16 in HW).
__device__ __forceinline__ void gll16(f16* lds, const f16* g){
  __builtin_amdgcn_global_load_lds(
      (const __attribute__((address_space(1))) void*)g,
      (__attribute__((address_space(3)))       void*)lds, 16, 0, 0);
}

// ---------------- RevIN stats ----------------
__global__ __launch_bounds__(256) void stats_kernel(const float* __restrict__ x,
    float* __restrict__ meanb, float* __restrict__ stdb)
{
  int i = blockIdx.x * 256 + threadIdx.x;
  if (i >= TT) return;
  int b = i / Nn, n = i - b * Nn;
  const float* p = x + (size_t)b * Lh * Nn + n;
  float s = 0.f, sq = 0.f;
  #pragma unroll 4
  for (int l = 0; l < Lh; l++){ float v = p[(size_t)l * Nn]; s += v; sq += v * v; }
  float m = s * (1.f / Lh);
  float var = sq * (1.f / Lh) - m * m;
  meanb[i] = m;
  stdb[i]  = sqrtf(var + EPSf);
}

// ---------------- normalize + layout to [tok][L] fp16 for embed GEMM ----------------
__global__ __launch_bounds__(256) void prep_kernel(const float* __restrict__ x,
    const float* __restrict__ meanb, const float* __restrict__ stdb,
    const float* __restrict__ rw, const float* __restrict__ rb,
    f16* __restrict__ xn16)
{
  int idx = blockIdx.x * 256 + threadIdx.x;
  if (idx >= Bb * Lh * Nn) return;
  int n  = idx % Nn;
  int bl = idx / Nn;
  int l  = bl % Lh;
  int b  = bl / Lh;
  int tok = b * Nn + n;
  float v = x[idx];
  xn16[(size_t)tok * Lh + l] = (f16)((v - meanb[tok]) / stdb[tok] * rw[n] + rb[n]);
}

// ---------------- f32 -> f16 convert (n must be multiple of 4) ----------------
__global__ __launch_bounds__(256) void cvt_kernel(const float* __restrict__ in,
    f16* __restrict__ out, int n4)
{
  int i = blockIdx.x * 256 + threadIdx.x;
  if (i >= n4) return;
  float4 v = ((const float4*)in)[i];
  f16x4 h; h[0] = (f16)v.x; h[1] = (f16)v.y; h[2] = (f16)v.z; h[3] = (f16)v.w;
  *(f16x4*)(out + (size_t)i * 4) = h;
}

// ---------------- MFMA GEMM: C[m,o] = act(sum_k A[m,k]*W[o,k] + bias[o]) ----------------
// A: [M,*] f16 (row stride lda halves). W: [O,K] f16 row-major. K multiple of 32.
// 128x128 tile, 4 waves (2x2), each wave 64x64 via 4x4 frags of 16x16x32.
// ACT: 0 none, 1 relu, 2 softplus. ACC: C += (requires W32). W32/W16: output f32/f16.
template<int ACT, int ACC, int W32, int W16>
__global__ __launch_bounds__(256) void gemm16_kernel(
    const f16* __restrict__ A, int lda,
    const f16* __restrict__ W, int K,
    const float* __restrict__ bias,
    float* __restrict__ C, int ldc,
    f16* __restrict__ C16, int ldc16,
    int O, int M)
{
  __shared__ f16 As[128 * 32];
  __shared__ f16 Bs[128 * 32];
  const int tid  = threadIdx.x;
  const int lane = tid & 63;
  const int w    = tid >> 6;
  const int wm   = w >> 1, wn = w & 1;
  const int m0   = blockIdx.y * 128, o0 = blockIdx.x * 128;
  const int lm   = lane & 15, kg = lane >> 4;
  const int sr0  = w * 32 + (lane >> 2);   // staging row (i=0); +16 for i=1
  const int sc   = (lane & 3) << 3;        // staging k offset (halves)

  f32x4 acc[4][4];
  #pragma unroll
  for (int i = 0; i < 4; i++)
    #pragma unroll
    for (int j = 0; j < 4; j++){ f32x4 z = {0.f,0.f,0.f,0.f}; acc[i][j] = z; }

  for (int k0 = 0; k0 < K; k0 += 32){
    __syncthreads();
    {
      int r0 = min(m0 + sr0,      M - 1);
      int r1 = min(m0 + sr0 + 16, M - 1);
      gll16(&As[w * 1024],       A + (size_t)r0 * lda + k0 + sc);
      gll16(&As[w * 1024 + 512], A + (size_t)r1 * lda + k0 + sc);
      int q0 = min(o0 + sr0,      O - 1);
      int q1 = min(o0 + sr0 + 16, O - 1);
      gll16(&Bs[w * 1024],       W + (size_t)q0 * K + k0 + sc);
      gll16(&Bs[w * 1024 + 512], W + (size_t)q1 * K + k0 + sc);
    }
    __syncthreads();   // compiler drains vmcnt before s_barrier
    f16x8 af[4], bf[4];
    #pragma unroll
    for (int f = 0; f < 4; f++){
      af[f] = *(const f16x8*)&As[(wm * 64 + f * 16 + lm) * 32 + kg * 8];
      bf[f] = *(const f16x8*)&Bs[(wn * 64 + f * 16 + lm) * 32 + kg * 8];
    }
    #pragma unroll
    for (int i = 0; i < 4; i++)
      #pragma unroll
      for (int j = 0; j < 4; j++)
        acc[i][j] = __builtin_amdgcn_mfma_f32_16x16x32_f16(af[i], bf[j], acc[i][j], 0, 0, 0);
  }

  // epilogue. C/D layout: col = lane&15, row = (lane>>4)*4 + r   [m89-verified]
  #pragma unroll
  for (int i = 0; i < 4; i++){
    #pragma unroll
    for (int r = 0; r < 4; r++){
      int m = m0 + wm * 64 + i * 16 + kg * 4 + r;
      if (m >= M) continue;
      #pragma unroll
      for (int j = 0; j < 4; j++){
        int o = o0 + wn * 64 + j * 16 + lm;
        if (o >= O) continue;
        float v = acc[i][j][r];
        if (bias) v += bias[o];
        if (ACT == 1) v = fmaxf(v, 0.f);
        if (ACT == 2) v = fmaxf(v, 0.f) + log1pf(__expf(-fabsf(v)));
        if (W32){
          float* p = C + (size_t)m * ldc + o;
          if (ACC) v += *p;
          *p = v;
        }
        if (W16) C16[(size_t)m * ldc16 + o] = (f16)v;
      }
    }
  }
}

// ---------------- depthwise causal conv (len 4) + SiLU, f16 in/out ----------------
__global__ __launch_bounds__(256) void conv_kernel(
    const f16* __restrict__ xz16, const float* __restrict__ w,
    const float* __restrict__ cb, f16* __restrict__ conv16, int dir, int Tc)
{
  int idx = blockIdx.x * 256 + threadIdx.x;
  if (idx >= Tc * Di) return;
  int tok = idx >> 10;
  int d   = idx & 1023;
  int n   = tok % Nn;
  const f16* base = xz16 + (size_t)(tok - n) * 2048 + d;
  float acc = cb[d];
  #pragma unroll
  for (int k = 0; k < 4; k++){
    int nn = dir ? (n + 3 - k) : (n - 3 + k);
    if (nn >= 0 && nn < Nn)
      acc = fmaf(w[(d << 2) + k], (float)base[(size_t)nn * 2048], acc);
  }
  conv16[idx] = (f16)(acc * sigm(acc));
}

// ---------------- selective scan (fp32 state), writes gated y as f16 ----------------
__global__ __launch_bounds__(256) void scan_kernel(
    const float* __restrict__ dtb, const f16* __restrict__ xz16,
    const f16* __restrict__ xi16, const float* __restrict__ dbc,
    const float* __restrict__ A_log, const float* __restrict__ Dp,
    f16* __restrict__ y16, int dir)
{
  int tid = blockIdx.x * 256 + threadIdx.x;
  int g  = tid & 3;
  int bd = tid >> 2;
  int d  = bd & 1023;
  int b  = bd >> 10;                  // chunk-local batch index
  float4 alog = *(const float4*)(A_log + (size_t)d * 16 + (g << 2));
  float Aj[4] = { -__expf(alog.x), -__expf(alog.y), -__expf(alog.z), -__expf(alog.w) };
  float Dpv = Dp[d];
  float h[4] = {0.f, 0.f, 0.f, 0.f};

  int tok_c;
  float dt_c, xv_c, zv_c; float4 B_c, C_c;
  {
    int n0 = dir ? (Nn - 1) : 0;
    tok_c = b * Nn + n0;
    dt_c = dtb[(size_t)tok_c * 1024 + d];
    zv_c = (float)xz16[(size_t)tok_c * 2048 + 1024 + d];
    xv_c = (float)xi16[(size_t)tok_c * 1024 + d];
    B_c  = *(const float4*)(dbc + (size_t)tok_c * 64 + 32 + (g << 2));
    C_c  = *(const float4*)(dbc + (size_t)tok_c * 64 + 48 + (g << 2));
  }
  for (int t = 0; t < Nn; t++){
    int tok_n = 0; float dt_n = 0.f, xv_n = 0.f, zv_n = 0.f;
    float4 B_n = make_float4(0,0,0,0), C_n = make_float4(0,0,0,0);
    if (t + 1 < Nn){
      int n0 = dir ? (Nn - 2 - t) : (t + 1);
      tok_n = b * Nn + n0;
      dt_n = dtb[(size_t)tok_n * 1024 + d];
      zv_n = (float)xz16[(size_t)tok_n * 2048 + 1024 + d];
      xv_n = (float)xi16[(size_t)tok_n * 1024 + d];
      B_n  = *(const float4*)(dbc + (size_t)tok_n * 64 + 32 + (g << 2));
      C_n  = *(const float4*)(dbc + (size_t)tok_n * 64 + 48 + (g << 2));
    }
    float dtx = dt_c * xv_c;
    float Br[4] = {B_c.x, B_c.y, B_c.z, B_c.w};
    float Cr[4] = {C_c.x, C_c.y, C_c.z, C_c.w};
    float y = 0.f;
    #pragma unroll
    for (int j = 0; j < 4; j++){
      float dA = __expf(dt_c * Aj[j]);
      h[j] = fmaf(dA, h[j], dtx * Br[j]);
      y = fmaf(h[j], Cr[j], y);
    }
    y += __shfl_xor(y, 1);
    y += __shfl_xor(y, 2);
    if (g == 0){
      float yy = y + xv_c * Dpv;
      y16[(size_t)tok_c * 1024 + d] = (f16)(yy * zv_c * sigm(zv_c));
    }
    tok_c = tok_n; dt_c = dt_n; xv_c = xv_n; zv_c = zv_n; B_c = B_n; C_c = C_n;
  }
}

// ---------------- (optional add) + LayerNorm over 512; writes fp32 e AND f16 e16 ----------------
__global__ __launch_bounds__(256) void add_ln_kernel(
    float* __restrict__ e, const float* __restrict__ add,
    const float* __restrict__ w, const float* __restrict__ bias,
    f16* __restrict__ e16)
{
  int wv = threadIdx.x >> 6, lane = threadIdx.x & 63;
  int tok = blockIdx.x * 4 + wv;
  float* p = e + (size_t)tok * Dm;
  float4 v0 = ((const float4*)p)[lane * 2];
  float4 v1 = ((const float4*)p)[lane * 2 + 1];
  float x[8] = {v0.x, v0.y, v0.z, v0.w, v1.x, v1.y, v1.z, v1.w};
  if (add){
    const float* q = add + (size_t)tok * Dm;
    float4 a0 = ((const float4*)q)[lane * 2];
    float4 a1 = ((const float4*)q)[lane * 2 + 1];
    x[0] += a0.x; x[1] += a0.y; x[2] += a0.z; x[3] += a0.w;
    x[4] += a1.x; x[5] += a1.y; x[6] += a1.z; x[7] += a1.w;
  }
  float s = 0.f;
  #pragma unroll
  for (int i = 0; i < 8; i++) s += x[i];
  #pragma unroll
  for (int off = 32; off; off >>= 1) s += __shfl_xor(s, off);
  float m = s * (1.f / Dm);
  float vv = 0.f;
  #pragma unroll
  for (int i = 0; i < 8; i++){ float dd = x[i] - m; vv += dd * dd; }
  #pragma unroll
  for (int off = 32; off; off >>= 1) vv += __shfl_xor(vv, off);
  float rs = rsqrtf(vv * (1.f / Dm) + EPSf);
  int db = lane * 8;
  float4 w0 = *(const float4*)(w + db),    w1 = *(const float4*)(w + db + 4);
  float4 b0 = *(const float4*)(bias + db), b1 = *(const float4*)(bias + db + 4);
  float wr[8] = {w0.x, w0.y, w0.z, w0.w, w1.x, w1.y, w1.z, w1.w};
  float br[8] = {b0.x, b0.y, b0.z, b0.w, b1.x, b1.y, b1.z, b1.w};
  float o[8];
  #pragma unroll
  for (int i = 0; i < 8; i++) o[i] = (x[i] - m) * rs * wr[i] + br[i];
  ((float4*)p)[lane * 2]     = make_float4(o[0], o[1], o[2], o[3]);
  ((float4*)p)[lane * 2 + 1] = make_float4(o[4], o[5], o[6], o[7]);
  f16x8 hv;
  #pragma unroll
  for (int i = 0; i < 8; i++) hv[i] = (f16)o[i];
  *(f16x8*)(e16 + (size_t)tok * Dm + db) = hv;
}

// ---------------- de-normalize + transpose to (B, FUT, N) ----------------
__global__ __launch_bounds__(256) void final_kernel(
    const float* __restrict__ dec, const float* __restrict__ meanb,
    const float* __restrict__ stdb, const float* __restrict__ rw,
    const float* __restrict__ rb, float* __restrict__ out)
{
  int idx = blockIdx.x * 256 + threadIdx.x;
  if (idx >= Bb * FUTc * Nn) return;
  int n  = idx % Nn;
  int bf = idx / Nn;
  int f  = bf % FUTc;
  int b  = bf / FUTc;
  int tok = b * Nn + n;
  float v = dec[(size_t)tok * FUTc + f];
  out[idx] = (v - rb[n]) / (rw[n] + 1e-10f) * stdb[tok] + meanb[tok];
}

extern "C" void kernel_launch(void* const* d_in, const int* in_sizes, int n_in,
                              void* d_out, int out_size, void* d_ws, size_t ws_size,
                              hipStream_t stream)
{
  const float* x_hist    = (const float*)d_in[0];
  const float* revin_w   = (const float*)d_in[1];
  const float* revin_b   = (const float*)d_in[2];
  const float* embed_w   = (const float*)d_in[3];
  const float* embed_b   = (const float*)d_in[4];
  const float* in_proj_w = (const float*)d_in[5];
  const float* conv_w    = (const float*)d_in[6];
  const float* conv_b    = (const float*)d_in[7];
  const float* x_proj_w  = (const float*)d_in[8];
  const float* dt_proj_w = (const float*)d_in[9];
  const float* dt_proj_b = (const float*)d_in[10];
  const float* A_log     = (const float*)d_in[11];
  const float* Dp        = (const float*)d_in[12];
  const float* out_proj_w= (const float*)d_in[13];
  const float* conv1_w   = (const float*)d_in[14];
  const float* conv1_b   = (const float*)d_in[15];
  const float* conv2_w   = (const float*)d_in[16];
  const float* conv2_b   = (const float*)d_in[17];
  const float* norm1_w   = (const float*)d_in[18];
  const float* norm1_b   = (const float*)d_in[19];
  const float* norm2_w   = (const float*)d_in[20];
  const float* norm2_b   = (const float*)d_in[21];
  const float* normf_w   = (const float*)d_in[22];
  const float* normf_b   = (const float*)d_in[23];
  const float* proj_w    = (const float*)d_in[24];
  const float* proj_b    = (const float*)d_in[25];

  // ---- workspace layout ----
  float* ws    = (float*)d_ws;
  float* meanb = ws;                                   // TT
  float* stdb  = ws + TT;                              // TT
  float* e     = ws + 2 * (size_t)TT;                  // TT*512 f32
  float* macc  = e    + (size_t)TT * Dm;               // TT*512 f32
  f16*   e16   = (f16*)(macc + (size_t)TT * Dm);       // TT*512 f16
  f16*   h16   = e16 + (size_t)TT * Dm;                // TT*512 f16 (FFN hidden)
  f16*   ipw16 = h16 + (size_t)TT * Dm;                // 4*2048*512
  f16*   opw16 = ipw16 + (size_t)4 * 2048 * Dm;        // 4*512*1024
  f16*   c1w16 = opw16 + (size_t)4 * Dm * Di;          // 2*512*512
  f16*   c2w16 = c1w16 + (size_t)2 * Dm * Dm;          // 2*512*512
  f16*   xpw16 = c2w16 + (size_t)2 * Dm * Dm;          // 4*64*1024
  f16*   dtw16 = xpw16 + (size_t)4 * 64 * Di;          // 4*1024*32
  f16*   emw16 = dtw16 + (size_t)4 * Di * DRr;         // 512*96
  f16*   prw16 = emw16 + (size_t)Dm * Lh;              // 96*512
  f16*   wend  = prw16 + (size_t)FUTc * Dm;
  float* chunk = (float*)(((uintptr_t)wend + 15) & ~(uintptr_t)15);
  size_t fixedb = (uintptr_t)chunk - (uintptr_t)ws;

  // per-token chunk floats: xz16(1024) conv16(512) dbc(64) dbc16(32) dtb(1024) y16(512) = 3168
  int Bc = 32;
  while (Bc > 1){
    size_t chunkf = (size_t)Bc * Nn * 3168;
    if (chunkf < (size_t)TT * 48) chunkf = (size_t)TT * 48;   // xn16 alias (TT*96 halves)
    if (fixedb + chunkf * sizeof(float) <= ws_size) break;
    Bc >>= 1;
  }
  f16*   xz16   = (f16*)chunk;                                   // [Tc][2048] f16
  f16*   conv16 = xz16 + (size_t)Bc * Nn * 2048;                 // [Tc][1024] f16
  float* dbc    = (float*)(conv16 + (size_t)Bc * Nn * 1024);     // [Tc][64] f32
  f16*   dbc16  = (f16*)(dbc + (size_t)Bc * Nn * 64);            // [Tc][64] f16
  float* dtb    = (float*)(dbc16 + (size_t)Bc * Nn * 64);        // [Tc][1024] f32
  f16*   y16    = (f16*)(dtb + (size_t)Bc * Nn * 1024);          // [Tc][1024] f16
  f16*   xn16   = (f16*)chunk;                                   // [TT][96] f16 (pre-loop alias)

  dim3 blk(256);
  auto cvt = [&](const float* in, f16* out, size_t n){
    int n4 = (int)(n / 4);
    cvt_kernel<<<(n4 + 255) / 256, blk, 0, stream>>>(in, out, n4);
  };
  cvt(in_proj_w,  ipw16, (size_t)4 * 2048 * Dm);
  cvt(out_proj_w, opw16, (size_t)4 * Dm * Di);
  cvt(conv1_w,    c1w16, (size_t)2 * Dm * Dm);
  cvt(conv2_w,    c2w16, (size_t)2 * Dm * Dm);
  cvt(x_proj_w,   xpw16, (size_t)4 * 64 * Di);
  cvt(dt_proj_w,  dtw16, (size_t)4 * Di * DRr);
  cvt(embed_w,    emw16, (size_t)Dm * Lh);
  cvt(proj_w,     prw16, (size_t)FUTc * Dm);

  stats_kernel<<<(TT + 255) / 256, blk, 0, stream>>>(x_hist, meanb, stdb);
  prep_kernel<<<(Bb * Lh * Nn + 255) / 256, blk, 0, stream>>>(x_hist, meanb, stdb, revin_w, revin_b, xn16);
  // embed: [TT,96] x [512,96] -> e (f32) + e16
  gemm16_kernel<0,0,1,1><<<dim3(4, (TT + 127) / 128), blk, 0, stream>>>(
      xn16, Lh, emw16, Lh, embed_b, e, Dm, e16, Dm, Dm, TT);

  const int Tc = Bc * Nn;
  const int gy = (Tc + 127) / 128;

  for (int l = 0; l < 2; l++){
    for (int dir = 0; dir < 2; dir++){
      int wi = l * 2 + dir;
      for (int b0 = 0; b0 < Bb; b0 += Bc){
        size_t tok0 = (size_t)b0 * Nn;
        // in_proj: [Tc,512] x [2048,512] -> xz16 [Tc,2048] f16
        gemm16_kernel<0,0,0,1><<<dim3(16, gy), blk, 0, stream>>>(
            e16 + tok0 * Dm, Dm, ipw16 + (size_t)wi * 2048 * Dm, Dm, nullptr,
            nullptr, 0, xz16, 2048, 2048, Tc);
        conv_kernel<<<((size_t)Tc * Di + 255) / 256, blk, 0, stream>>>(
            xz16, conv_w + (size_t)wi * Di * 4, conv_b + (size_t)wi * Di, conv16, dir, Tc);
        // x_proj: [Tc,1024] x [64,1024] -> dbc f32 + dbc16
        gemm16_kernel<0,0,1,1><<<dim3(1, gy), blk, 0, stream>>>(
            conv16, Di, xpw16 + (size_t)wi * 64 * Di, Di, nullptr,
            dbc, 64, dbc16, 64, 64, Tc);
        // dt_proj + softplus: [Tc,32] x [1024,32] -> dtb f32
        gemm16_kernel<2,0,1,0><<<dim3(8, gy), blk, 0, stream>>>(
            dbc16, 64, dtw16 + (size_t)wi * Di * DRr, DRr, dt_proj_b + (size_t)wi * Di,
            dtb, Di, nullptr, 0, Di, Tc);
        scan_kernel<<<Bc * 16, blk, 0, stream>>>(
            dtb, xz16, conv16, dbc, A_log + (size_t)wi * Di * Ds, Dp + (size_t)wi * Di, y16, dir);
        // out_proj: [Tc,1024] x [512,1024] -> macc f32 (accumulate dir 1)
        if (dir == 0)
          gemm16_kernel<0,0,1,0><<<dim3(4, gy), blk, 0, stream>>>(
              y16, Di, opw16 + (size_t)wi * Dm * Di, Di, nullptr,
              macc + tok0 * Dm, Dm, nullptr, 0, Dm, Tc);
        else
          gemm16_kernel<0,1,1,0><<<dim3(4, gy), blk, 0, stream>>>(
              y16, Di, opw16 + (size_t)wi * Dm * Di, Di, nullptr,
              macc + tok0 * Dm, Dm, nullptr, 0, Dm, Tc);
      }
    }
    add_ln_kernel<<<TT / 4, blk, 0, stream>>>(e, macc, norm1_w + l * Dm, norm1_b + l * Dm, e16);
    // FFN conv1 (relu) -> h16 (f16 only)
    gemm16_kernel<1,0,0,1><<<dim3(4, (TT + 127) / 128), blk, 0, stream>>>(
        e16, Dm, c1w16 + (size_t)l * Dm * Dm, Dm, conv1_b + l * Dm,
        nullptr, 0, h16, Dm, Dm, TT);
    // conv2 -> fp32 tmp in chunk region (row-chunked), then add+LN
    {
      size_t chunkf = (size_t)Bc * Nn * 3168;
      if (chunkf < (size_t)TT * 48) chunkf = (size_t)TT * 48;
      int rows = (int)(chunkf / Dm);
      if (rows > TT) rows = TT;
      rows &= ~127;
      if (rows < 128) rows = 128;
      for (int r0 = 0; r0 < TT; r0 += rows){
        int rc = min(rows, TT - r0);
        gemm16_kernel<0,0,1,0><<<dim3(4, (rc + 127) / 128), blk, 0, stream>>>(
            h16 + (size_t)r0 * Dm, Dm, c2w16 + (size_t)l * Dm * Dm, Dm, conv2_b + l * Dm,
            chunk, Dm, nullptr, 0, Dm, rc);
        add_ln_kernel<<<rc / 4, blk, 0, stream>>>(
            e + (size_t)r0 * Dm, chunk, norm2_w + l * Dm, norm2_b + l * Dm, e16 + (size_t)r0 * Dm);
      }
    }
  }

  add_ln_kernel<<<TT / 4, blk, 0, stream>>>(e, nullptr, normf_w, normf_b, e16);
  // proj: [TT,512] x [96,512] -> dec f32 in macc
  gemm16_kernel<0,0,1,0><<<dim3(1, (TT + 127) / 128), blk, 0, stream>>>(
      e16, Dm, prw16, Dm, proj_b, macc, FUTc, nullptr, 0, FUTc, TT);
  final_kernel<<<(Bb * FUTc * Nn + 255) / 256, blk, 0, stream>>>(
      macc, meanb, stdb, revin_w, revin_b, (float*)d_out);
}

// Round 2
// 4997.014 us; speedup vs baseline: 3.2098x; 3.2098x over previous
//
#include <hip/hip_runtime.h>

// SDMamba forward. All GEMMs on MFMA f16 (fp32 accumulate); conv/scan/LN fp32 math.
// Full-batch everywhere (fits known ws >= 229 MB): one scan per (layer,dir).
// z is never stored: gate applied by a post-scan GEMM epilogue (f16 RMW).
// dt computed inside the scan (dot8 + softplus), 8-deep register-FIFO prefetch.

typedef _Float16 f16;
typedef _Float16 f16x8 __attribute__((ext_vector_type(8)));
typedef _Float16 f16x4 __attribute__((ext_vector_type(4)));
typedef float    f32x4 __attribute__((ext_vector_type(4)));

constexpr int Bb  = 32;
constexpr int Lh  = 96;
constexpr int FUTc= 96;
constexpr int Nn  = 862;
constexpr int Dm  = 512;
constexpr int Ds  = 16;
constexpr int Di  = 1024;
constexpr int DRr = 32;
constexpr int TT  = Bb * Nn;     // 27584
constexpr float EPSf = 1e-5f;
constexpr int PF = 8;            // scan prefetch depth

__device__ __forceinline__ float sigm(float x){ return 1.f / (1.f + __expf(-x)); }

__device__ __forceinline__ void gll16(f16* lds, const f16* g){
  __builtin_amdgcn_global_load_lds(
      (const __attribute__((address_space(1))) void*)g,
      (__attribute__((address_space(3)))       void*)lds, 16, 0, 0);
}

// ---------------- RevIN stats ----------------
__global__ __launch_bounds__(256) void stats_kernel(const float* __restrict__ x,
    float* __restrict__ meanb, float* __restrict__ stdb)
{
  int i = blockIdx.x * 256 + threadIdx.x;
  if (i >= TT) return;
  int b = i / Nn, n = i - b * Nn;
  const float* p = x + (size_t)b * Lh * Nn + n;
  float s = 0.f, sq = 0.f;
  #pragma unroll 4
  for (int l = 0; l < Lh; l++){ float v = p[(size_t)l * Nn]; s += v; sq += v * v; }
  float m = s * (1.f / Lh);
  float var = sq * (1.f / Lh) - m * m;
  meanb[i] = m;
  stdb[i]  = sqrtf(var + EPSf);
}

// ---------------- normalize + layout to [tok][L] fp16 ----------------
__global__ __launch_bounds__(256) void prep_kernel(const float* __restrict__ x,
    const float* __restrict__ meanb, const float* __restrict__ stdb,
    const float* __restrict__ rw, const float* __restrict__ rb,
    f16* __restrict__ xn16)
{
  int idx = blockIdx.x * 256 + threadIdx.x;
  if (idx >= Bb * Lh * Nn) return;
  int n  = idx % Nn;
  int bl = idx / Nn;
  int l  = bl % Lh;
  int b  = bl / Lh;
  int tok = b * Nn + n;
  float v = x[idx];
  xn16[(size_t)tok * Lh + l] = (f16)((v - meanb[tok]) / stdb[tok] * rw[n] + rb[n]);
}

// ---------------- f32 -> f16 convert ----------------
__global__ __launch_bounds__(256) void cvt_kernel(const float* __restrict__ in,
    f16* __restrict__ out, int n4)
{
  int i = blockIdx.x * 256 + threadIdx.x;
  if (i >= n4) return;
  float4 v = ((const float4*)in)[i];
  f16x4 h; h[0] = (f16)v.x; h[1] = (f16)v.y; h[2] = (f16)v.z; h[3] = (f16)v.w;
  *(f16x4*)(out + (size_t)i * 4) = h;
}

// ---------------- MFMA GEMM: C[m,o] = act(sum_k A[m,k]*W[o,k] + bias[o]) ----------------
// ACT: 0 none, 1 relu, 2 softplus, 3 silu-gate-RMW on C16 (C16 *= silu(v)).
// ACC: C += (W32 path). W32/W16: write f32 C / f16 C16.
template<int ACT, int ACC, int W32, int W16>
__global__ __launch_bounds__(256) void gemm16_kernel(
    const f16* __restrict__ A, int lda,
    const f16* __restrict__ W, int K,
    const float* __restrict__ bias,
    float* __restrict__ C, int ldc,
    f16* __restrict__ C16, int ldc16,
    int O, int M)
{
  __shared__ f16 As[128 * 32];
  __shared__ f16 Bs[128 * 32];
  const int tid  = threadIdx.x;
  const int lane = tid & 63;
  const int w    = tid >> 6;
  const int wm   = w >> 1, wn = w & 1;
  const int m0   = blockIdx.y * 128, o0 = blockIdx.x * 128;
  const int lm   = lane & 15, kg = lane >> 4;
  const int sr0  = w * 32 + (lane >> 2);
  const int sc   = (lane & 3) << 3;

  f32x4 acc[4][4];
  #pragma unroll
  for (int i = 0; i < 4; i++)
    #pragma unroll
    for (int j = 0; j < 4; j++){ f32x4 z = {0.f,0.f,0.f,0.f}; acc[i][j] = z; }

  for (int k0 = 0; k0 < K; k0 += 32){
    __syncthreads();
    {
      int r0 = min(m0 + sr0,      M - 1);
      int r1 = min(m0 + sr0 + 16, M - 1);
      gll16(&As[w * 1024],       A + (size_t)r0 * lda + k0 + sc);
      gll16(&As[w * 1024 + 512], A + (size_t)r1 * lda + k0 + sc);
      int q0 = min(o0 + sr0,      O - 1);
      int q1 = min(o0 + sr0 + 16, O - 1);
      gll16(&Bs[w * 1024],       W + (size_t)q0 * K + k0 + sc);
      gll16(&Bs[w * 1024 + 512], W + (size_t)q1 * K + k0 + sc);
    }
    __syncthreads();
    f16x8 af[4], bf[4];
    #pragma unroll
    for (int f = 0; f < 4; f++){
      af[f] = *(const f16x8*)&As[(wm * 64 + f * 16 + lm) * 32 + kg * 8];
      bf[f] = *(const f16x8*)&Bs[(wn * 64 + f * 16 + lm) * 32 + kg * 8];
    }
    #pragma unroll
    for (int i = 0; i < 4; i++)
      #pragma unroll
      for (int j = 0; j < 4; j++)
        acc[i][j] = __builtin_amdgcn_mfma_f32_16x16x32_f16(af[i], bf[j], acc[i][j], 0, 0, 0);
  }

  #pragma unroll
  for (int i = 0; i < 4; i++){
    #pragma unroll
    for (int r = 0; r < 4; r++){
      int m = m0 + wm * 64 + i * 16 + kg * 4 + r;
      if (m >= M) continue;
      #pragma unroll
      for (int j = 0; j < 4; j++){
        int o = o0 + wn * 64 + j * 16 + lm;
        if (o >= O) continue;
        float v = acc[i][j][r];
        if (bias) v += bias[o];
        if (ACT == 1) v = fmaxf(v, 0.f);
        if (ACT == 2) v = fmaxf(v, 0.f) + log1pf(__expf(-fabsf(v)));
        if (ACT == 3){
          float gate = v * sigm(v);
          f16* p16 = C16 + (size_t)m * ldc16 + o;
          *p16 = (f16)((float)*p16 * gate);
        } else {
          if (W32){
            float* p = C + (size_t)m * ldc + o;
            if (ACC) v += *p;
            *p = v;
          }
          if (W16) C16[(size_t)m * ldc16 + o] = (f16)v;
        }
      }
    }
  }
}

// ---------------- depthwise causal conv (len 4) + SiLU ----------------
__global__ __launch_bounds__(256) void conv_kernel(
    const f16* __restrict__ x16, const float* __restrict__ w,
    const float* __restrict__ cb, f16* __restrict__ xi16, int dir)
{
  int idx = blockIdx.x * 256 + threadIdx.x;
  if (idx >= TT * Di) return;
  int tok = idx >> 10;
  int d   = idx & 1023;
  int n   = tok % Nn;
  const f16* base = x16 + (size_t)(tok - n) * 1024 + d;
  float acc = cb[d];
  #pragma unroll
  for (int k = 0; k < 4; k++){
    int nn = dir ? (n + 3 - k) : (n - 3 + k);
    if (nn >= 0 && nn < Nn)
      acc = fmaf(w[(d << 2) + k], (float)base[(size_t)nn * 1024], acc);
  }
  xi16[idx] = (f16)(acc * sigm(acc));
}

// ---------------- selective scan: dt in-scan, 8-deep register FIFO ----------------
// y buffer: in = xi (silu(conv)), out = ungated y (y + xi*Dp), overwritten in place.
__global__ __launch_bounds__(256) void scan2_kernel(
    const f16* __restrict__ dbc16, const float* __restrict__ dbc,
    f16* __restrict__ y,
    const f16* __restrict__ dtw, const float* __restrict__ dtb,
    const float* __restrict__ A_log, const float* __restrict__ Dp, int dir)
{
  int tid  = blockIdx.x * 256 + threadIdx.x;
  int g    = tid & 3;
  int chain= tid >> 2;
  int d    = chain & 1023;
  int b    = chain >> 10;
  float4 alog = *(const float4*)(A_log + (size_t)d * 16 + (g << 2));
  float Aj[4] = { -__expf(alog.x), -__expf(alog.y), -__expf(alog.z), -__expf(alog.w) };
  float Dpv  = Dp[d];
  float bias = dtb[d];
  f16x8 wdt  = *(const f16x8*)(dtw + (size_t)d * 32 + (g << 3));
  const size_t base = (size_t)b * Nn;
  float h[4] = {0.f, 0.f, 0.f, 0.f};

  f16x8  dtF[PF];
  float4 BF[PF], CF[PF];
  f16    xiF[PF];

  #pragma unroll
  for (int s = 0; s < PF; s++){
    int n = dir ? (Nn - 1 - s) : s;
    size_t tok = base + n;
    dtF[s] = *(const f16x8*)(dbc16 + tok * 64 + (g << 3));
    BF[s]  = *(const float4*)(dbc + tok * 64 + 32 + (g << 2));
    CF[s]  = *(const float4*)(dbc + tok * 64 + 48 + (g << 2));
    xiF[s] = y[tok * 1024 + d];
  }

  for (int t0 = 0; t0 < Nn; t0 += PF){
    #pragma unroll
    for (int s = 0; s < PF; s++){
      int t = t0 + s;
      if (t < Nn){
        int n = dir ? (Nn - 1 - t) : t;
        size_t tok = base + n;
        // dt = softplus(dt_in . dtw + bias), 8 elems per lane + 4-lane reduce
        float dtp = 0.f;
        #pragma unroll
        for (int i = 0; i < 8; i++) dtp += (float)dtF[s][i] * (float)wdt[i];
        dtp += __shfl_xor(dtp, 1);
        dtp += __shfl_xor(dtp, 2);
        float v  = dtp + bias;
        float dt = fmaxf(v, 0.f) + log1pf(__expf(-fabsf(v)));
        float xv = (float)xiF[s];
        float dtx = dt * xv;
        float Br[4] = {BF[s].x, BF[s].y, BF[s].z, BF[s].w};
        float Cr[4] = {CF[s].x, CF[s].y, CF[s].z, CF[s].w};
        float yv = 0.f;
        #pragma unroll
        for (int j = 0; j < 4; j++){
          float dA = __expf(dt * Aj[j]);
          h[j] = fmaf(dA, h[j], dtx * Br[j]);
          yv = fmaf(h[j], Cr[j], yv);
        }
        yv += __shfl_xor(yv, 1);
        yv += __shfl_xor(yv, 2);
        if (g == 0) y[tok * 1024 + d] = (f16)(yv + xv * Dpv);
        // refill slot s with token t+PF
        int tn = t + PF;
        if (tn < Nn){
          int n2 = dir ? (Nn - 1 - tn) : tn;
          size_t tok2 = base + n2;
          dtF[s] = *(const f16x8*)(dbc16 + tok2 * 64 + (g << 3));
          BF[s]  = *(const float4*)(dbc + tok2 * 64 + 32 + (g << 2));
          CF[s]  = *(const float4*)(dbc + tok2 * 64 + 48 + (g << 2));
          xiF[s] = y[tok2 * 1024 + d];
        }
      }
    }
  }
}

// ---------------- (optional add) + LayerNorm; writes f32 e AND f16 e16 ----------------
__global__ __launch_bounds__(256) void add_ln_kernel(
    float* __restrict__ e, const float* __restrict__ add,
    const float* __restrict__ w, const float* __restrict__ bias,
    f16* __restrict__ e16)
{
  int wv = threadIdx.x >> 6, lane = threadIdx.x & 63;
  int tok = blockIdx.x * 4 + wv;
  float* p = e + (size_t)tok * Dm;
  float4 v0 = ((const float4*)p)[lane * 2];
  float4 v1 = ((const float4*)p)[lane * 2 + 1];
  float x[8] = {v0.x, v0.y, v0.z, v0.w, v1.x, v1.y, v1.z, v1.w};
  if (add){
    const float* q = add + (size_t)tok * Dm;
    float4 a0 = ((const float4*)q)[lane * 2];
    float4 a1 = ((const float4*)q)[lane * 2 + 1];
    x[0] += a0.x; x[1] += a0.y; x[2] += a0.z; x[3] += a0.w;
    x[4] += a1.x; x[5] += a1.y; x[6] += a1.z; x[7] += a1.w;
  }
  float s = 0.f;
  #pragma unroll
  for (int i = 0; i < 8; i++) s += x[i];
  #pragma unroll
  for (int off = 32; off; off >>= 1) s += __shfl_xor(s, off);
  float m = s * (1.f / Dm);
  float vv = 0.f;
  #pragma unroll
  for (int i = 0; i < 8; i++){ float dd = x[i] - m; vv += dd * dd; }
  #pragma unroll
  for (int off = 32; off; off >>= 1) vv += __shfl_xor(vv, off);
  float rs = rsqrtf(vv * (1.f / Dm) + EPSf);
  int db = lane * 8;
  float4 w0 = *(const float4*)(w + db),    w1 = *(const float4*)(w + db + 4);
  float4 b0 = *(const float4*)(bias + db), b1 = *(const float4*)(bias + db + 4);
  float wr[8] = {w0.x, w0.y, w0.z, w0.w, w1.x, w1.y, w1.z, w1.w};
  float br[8] = {b0.x, b0.y, b0.z, b0.w, b1.x, b1.y, b1.z, b1.w};
  float o[8];
  #pragma unroll
  for (int i = 0; i < 8; i++) o[i] = (x[i] - m) * rs * wr[i] + br[i];
  ((float4*)p)[lane * 2]     = make_float4(o[0], o[1], o[2], o[3]);
  ((float4*)p)[lane * 2 + 1] = make_float4(o[4], o[5], o[6], o[7]);
  f16x8 hv;
  #pragma unroll
  for (int i = 0; i < 8; i++) hv[i] = (f16)o[i];
  *(f16x8*)(e16 + (size_t)tok * Dm + db) = hv;
}

// ---------------- de-normalize + transpose to (B, FUT, N) ----------------
__global__ __launch_bounds__(256) void final_kernel(
    const float* __restrict__ dec, const float* __restrict__ meanb,
    const float* __restrict__ stdb, const float* __restrict__ rw,
    const float* __restrict__ rb, float* __restrict__ out)
{
  int idx = blockIdx.x * 256 + threadIdx.x;
  if (idx >= Bb * FUTc * Nn) return;
  int n  = idx % Nn;
  int bf = idx / Nn;
  int f  = bf % FUTc;
  int b  = bf / FUTc;
  int tok = b * Nn + n;
  float v = dec[(size_t)tok * FUTc + f];
  out[idx] = (v - rb[n]) / (rw[n] + 1e-10f) * stdb[tok] + meanb[tok];
}

extern "C" void kernel_launch(void* const* d_in, const int* in_sizes, int n_in,
                              void* d_out, int out_size, void* d_ws, size_t ws_size,
                              hipStream_t stream)
{
  const float* x_hist    = (const float*)d_in[0];
  const float* revin_w   = (const float*)d_in[1];
  const float* revin_b   = (const float*)d_in[2];
  const float* embed_w   = (const float*)d_in[3];
  const float* embed_b   = (const float*)d_in[4];
  const float* in_proj_w = (const float*)d_in[5];
  const float* conv_w    = (const float*)d_in[6];
  const float* conv_b    = (const float*)d_in[7];
  const float* x_proj_w  = (const float*)d_in[8];
  const float* dt_proj_w = (const float*)d_in[9];
  const float* dt_proj_b = (const float*)d_in[10];
  const float* A_log     = (const float*)d_in[11];
  const float* Dp        = (const float*)d_in[12];
  const float* out_proj_w= (const float*)d_in[13];
  const float* conv1_w   = (const float*)d_in[14];
  const float* conv1_b   = (const float*)d_in[15];
  const float* conv2_w   = (const float*)d_in[16];
  const float* conv2_b   = (const float*)d_in[17];
  const float* norm1_w   = (const float*)d_in[18];
  const float* norm1_b   = (const float*)d_in[19];
  const float* norm2_w   = (const float*)d_in[20];
  const float* norm2_b   = (const float*)d_in[21];
  const float* normf_w   = (const float*)d_in[22];
  const float* normf_b   = (const float*)d_in[23];
  const float* proj_w    = (const float*)d_in[24];
  const float* proj_b    = (const float*)d_in[25];

  // ---- workspace layout (224.2 MB total; known ws >= 229.0 MB) ----
  float* ws    = (float*)d_ws;
  float* meanb = ws;                                    // TT f32
  float* stdb  = meanb + TT;                            // TT f32
  float* e     = stdb + TT;                             // TT*512 f32
  f16*   e16   = (f16*)(e + (size_t)TT * Dm);           // TT*512 f16
  f16*   x16   = e16 + (size_t)TT * Dm;                 // TT*1024 f16
  f16*   xi16  = x16 + (size_t)TT * Di;                 // TT*1024 f16 (scan writes y in place)
  float* dbc   = (float*)(xi16 + (size_t)TT * Di);      // TT*64 f32
  f16*   dbc16 = (f16*)(dbc + (size_t)TT * 64);         // TT*64 f16
  f16*   ipw16 = dbc16 + (size_t)TT * 64;               // 4*2048*512
  f16*   opw16 = ipw16 + (size_t)4 * 2048 * Dm;         // 4*512*1024
  f16*   c1w16 = opw16 + (size_t)4 * Dm * Di;           // 2*512*512
  f16*   c2w16 = c1w16 + (size_t)2 * Dm * Dm;           // 2*512*512
  f16*   xpw16 = c2w16 + (size_t)2 * Dm * Dm;           // 4*64*1024
  f16*   dtw16 = xpw16 + (size_t)4 * 64 * Di;           // 4*1024*32
  f16*   emw16 = dtw16 + (size_t)4 * Di * DRr;          // 512*96
  f16*   prw16 = emw16 + (size_t)Dm * Lh;               // 96*512

  // aliases into freed regions
  f16*   xn16  = x16;               // [TT][96] embed staging (pre-loop)
  f16*   h16   = xi16;              // [TT][512] FFN hidden (post-mamba)
  float* ftmp  = (float*)x16;       // [TT][512] f32 conv2 out (x16 free post-conv)
  float* dec   = (float*)x16;       // [TT][96] f32 final projection

  dim3 blk(256);
  auto cvt = [&](const float* in, f16* out, size_t n){
    int n4 = (int)(n / 4);
    cvt_kernel<<<(n4 + 255) / 256, blk, 0, stream>>>(in, out, n4);
  };
  cvt(in_proj_w,  ipw16, (size_t)4 * 2048 * Dm);
  cvt(out_proj_w, opw16, (size_t)4 * Dm * Di);
  cvt(conv1_w,    c1w16, (size_t)2 * Dm * Dm);
  cvt(conv2_w,    c2w16, (size_t)2 * Dm * Dm);
  cvt(x_proj_w,   xpw16, (size_t)4 * 64 * Di);
  cvt(dt_proj_w,  dtw16, (size_t)4 * Di * DRr);
  cvt(embed_w,    emw16, (size_t)Dm * Lh);
  cvt(proj_w,     prw16, (size_t)FUTc * Dm);

  stats_kernel<<<(TT + 255) / 256, blk, 0, stream>>>(x_hist, meanb, stdb);
  prep_kernel<<<(Bb * Lh * Nn + 255) / 256, blk, 0, stream>>>(x_hist, meanb, stdb, revin_w, revin_b, xn16);

  const int gy = (TT + 127) / 128;   // 216
  // embed: [TT,96] x [512,96] -> e (f32) + e16
  gemm16_kernel<0,0,1,1><<<dim3(4, gy), blk, 0, stream>>>(
      xn16, Lh, emw16, Lh, embed_b, e, Dm, e16, Dm, Dm, TT);

  for (int l = 0; l < 2; l++){
    for (int dir = 0; dir < 2; dir++){
      int wi = l * 2 + dir;
      const f16* Wx = ipw16 + (size_t)wi * 2048 * Dm;           // rows 0..1023 (x half)
      const f16* Wz = Wx + (size_t)Di * Dm;                     // rows 1024..2047 (z half)
      // in_proj x-half: [TT,512] x [1024,512] -> x16 f16
      gemm16_kernel<0,0,0,1><<<dim3(8, gy), blk, 0, stream>>>(
          e16, Dm, Wx, Dm, nullptr, nullptr, 0, x16, Di, Di, TT);
      // depthwise conv + silu -> xi16
      conv_kernel<<<((size_t)TT * Di + 255) / 256, blk, 0, stream>>>(
          x16, conv_w + (size_t)wi * Di * 4, conv_b + (size_t)wi * Di, xi16, dir);
      // x_proj: [TT,1024] x [64,1024] -> dbc f32 + dbc16 f16
      gemm16_kernel<0,0,1,1><<<dim3(1, gy), blk, 0, stream>>>(
          xi16, Di, xpw16 + (size_t)wi * 64 * Di, Di, nullptr,
          dbc, 64, dbc16, 64, 64, TT);
      // scan (dt in-scan); xi16 -> ungated y in place
      scan2_kernel<<<Bb * 16, blk, 0, stream>>>(
          dbc16, dbc, xi16,
          dtw16 + (size_t)wi * Di * DRr, dt_proj_b + (size_t)wi * Di,
          A_log + (size_t)wi * Di * Ds, Dp + (size_t)wi * Di, dir);
      // gate: y *= silu(e16 @ Wz^T)   (f16 RMW epilogue)
      gemm16_kernel<3,0,0,1><<<dim3(8, gy), blk, 0, stream>>>(
          e16, Dm, Wz, Dm, nullptr, nullptr, 0, xi16, Di, Di, TT);
      // out_proj: [TT,1024] x [512,1024] -> e += (residual accumulate)
      gemm16_kernel<0,1,1,0><<<dim3(4, gy), blk, 0, stream>>>(
          xi16, Di, opw16 + (size_t)wi * Dm * Di, Di, nullptr,
          e, Dm, nullptr, 0, Dm, TT);
    }
    // e = LN(e) (mf+mr already accumulated); regenerate e16
    add_ln_kernel<<<TT / 4, blk, 0, stream>>>(e, nullptr, norm1_w + l * Dm, norm1_b + l * Dm, e16);
    // FFN: conv1 relu -> h16 (aliases xi16)
    gemm16_kernel<1,0,0,1><<<dim3(4, gy), blk, 0, stream>>>(
        e16, Dm, c1w16 + (size_t)l * Dm * Dm, Dm, conv1_b + l * Dm,
        nullptr, 0, h16, Dm, Dm, TT);
    // conv2 -> ftmp f32 (aliases x16)
    gemm16_kernel<0,0,1,0><<<dim3(4, gy), blk, 0, stream>>>(
        h16, Dm, c2w16 + (size_t)l * Dm * Dm, Dm, conv2_b + l * Dm,
        ftmp, Dm, nullptr, 0, Dm, TT);
    add_ln_kernel<<<TT / 4, blk, 0, stream>>>(e, ftmp, norm2_w + l * Dm, norm2_b + l * Dm, e16);
  }

  add_ln_kernel<<<TT / 4, blk, 0, stream>>>(e, nullptr, normf_w, normf_b, e16);
  // proj: [TT,512] x [96,512] -> dec f32
  gemm16_kernel<0,0,1,0><<<dim3(1, gy), blk, 0, stream>>>(
      e16, Dm, prw16, Dm, proj_b, dec, FUTc, nullptr, 0, FUTc, TT);
  final_kernel<<<(Bb * FUTc * Nn + 255) / 256, blk, 0, stream>>>(
      dec, meanb, stdb, revin_w, revin_b, (float*)d_out);
}

// Round 3
// 4530.079 us; speedup vs baseline: 3.5406x; 1.1031x over previous
//
#include <hip/hip_runtime.h>

// SDMamba forward. All GEMMs on MFMA f16 (fp32 accumulate); conv/scan/LN fp32 math.
// Full-batch; one scan per (layer,dir). Scan reads xi16, writes y into x16
// (distinct buffers -> no alias -> register FIFO prefetch actually pipelines).

typedef _Float16 f16;
typedef _Float16 f16x8 __attribute__((ext_vector_type(8)));
typedef _Float16 f16x4 __attribute__((ext_vector_type(4)));
typedef float    f32x4 __attribute__((ext_vector_type(4)));

constexpr int Bb  = 32;
constexpr int Lh  = 96;
constexpr int FUTc= 96;
constexpr int Nn  = 862;
constexpr int Dm  = 512;
constexpr int Ds  = 16;
constexpr int Di  = 1024;
constexpr int DRr = 32;
constexpr int TT  = Bb * Nn;     // 27584
constexpr float EPSf = 1e-5f;
constexpr int PF = 8;            // scan prefetch depth

__device__ __forceinline__ float sigm(float x){ return 1.f / (1.f + __expf(-x)); }

__device__ __forceinline__ void gll16(f16* lds, const f16* g){
  __builtin_amdgcn_global_load_lds(
      (const __attribute__((address_space(1))) void*)g,
      (__attribute__((address_space(3)))       void*)lds, 16, 0, 0);
}

// ---------------- RevIN stats ----------------
__global__ __launch_bounds__(256) void stats_kernel(const float* __restrict__ x,
    float* __restrict__ meanb, float* __restrict__ stdb)
{
  int i = blockIdx.x * 256 + threadIdx.x;
  if (i >= TT) return;
  int b = i / Nn, n = i - b * Nn;
  const float* p = x + (size_t)b * Lh * Nn + n;
  float s = 0.f, sq = 0.f;
  #pragma unroll 4
  for (int l = 0; l < Lh; l++){ float v = p[(size_t)l * Nn]; s += v; sq += v * v; }
  float m = s * (1.f / Lh);
  float var = sq * (1.f / Lh) - m * m;
  meanb[i] = m;
  stdb[i]  = sqrtf(var + EPSf);
}

// ---------------- normalize + layout to [tok][L] fp16 ----------------
__global__ __launch_bounds__(256) void prep_kernel(const float* __restrict__ x,
    const float* __restrict__ meanb, const float* __restrict__ stdb,
    const float* __restrict__ rw, const float* __restrict__ rb,
    f16* __restrict__ xn16)
{
  int idx = blockIdx.x * 256 + threadIdx.x;
  if (idx >= Bb * Lh * Nn) return;
  int n  = idx % Nn;
  int bl = idx / Nn;
  int l  = bl % Lh;
  int b  = bl / Lh;
  int tok = b * Nn + n;
  float v = x[idx];
  xn16[(size_t)tok * Lh + l] = (f16)((v - meanb[tok]) / stdb[tok] * rw[n] + rb[n]);
}

// ---------------- f32 -> f16 convert ----------------
__global__ __launch_bounds__(256) void cvt_kernel(const float* __restrict__ in,
    f16* __restrict__ out, int n4)
{
  int i = blockIdx.x * 256 + threadIdx.x;
  if (i >= n4) return;
  float4 v = ((const float4*)in)[i];
  f16x4 h; h[0] = (f16)v.x; h[1] = (f16)v.y; h[2] = (f16)v.z; h[3] = (f16)v.w;
  *(f16x4*)(out + (size_t)i * 4) = h;
}

// ---------------- MFMA GEMM: C[m,o] = act(sum_k A[m,k]*W[o,k] + bias[o]) ----------------
// ACT: 0 none, 1 relu, 2 softplus, 3 silu-gate-RMW on C16 (C16 *= silu(v)).
// ACC: C += (W32 path). W32/W16: write f32 C / f16 C16.
template<int ACT, int ACC, int W32, int W16>
__global__ __launch_bounds__(256) void gemm16_kernel(
    const f16* __restrict__ A, int lda,
    const f16* __restrict__ W, int K,
    const float* __restrict__ bias,
    float* __restrict__ C, int ldc,
    f16* __restrict__ C16, int ldc16,
    int O, int M)
{
  __shared__ f16 As[128 * 32];
  __shared__ f16 Bs[128 * 32];
  const int tid  = threadIdx.x;
  const int lane = tid & 63;
  const int w    = tid >> 6;
  const int wm   = w >> 1, wn = w & 1;
  const int m0   = blockIdx.y * 128, o0 = blockIdx.x * 128;
  const int lm   = lane & 15, kg = lane >> 4;
  const int sr0  = w * 32 + (lane >> 2);
  const int sc   = (lane & 3) << 3;

  f32x4 acc[4][4];
  #pragma unroll
  for (int i = 0; i < 4; i++)
    #pragma unroll
    for (int j = 0; j < 4; j++){ f32x4 z = {0.f,0.f,0.f,0.f}; acc[i][j] = z; }

  for (int k0 = 0; k0 < K; k0 += 32){
    __syncthreads();
    {
      int r0 = min(m0 + sr0,      M - 1);
      int r1 = min(m0 + sr0 + 16, M - 1);
      gll16(&As[w * 1024],       A + (size_t)r0 * lda + k0 + sc);
      gll16(&As[w * 1024 + 512], A + (size_t)r1 * lda + k0 + sc);
      int q0 = min(o0 + sr0,      O - 1);
      int q1 = min(o0 + sr0 + 16, O - 1);
      gll16(&Bs[w * 1024],       W + (size_t)q0 * K + k0 + sc);
      gll16(&Bs[w * 1024 + 512], W + (size_t)q1 * K + k0 + sc);
    }
    __syncthreads();
    f16x8 af[4], bf[4];
    #pragma unroll
    for (int f = 0; f < 4; f++){
      af[f] = *(const f16x8*)&As[(wm * 64 + f * 16 + lm) * 32 + kg * 8];
      bf[f] = *(const f16x8*)&Bs[(wn * 64 + f * 16 + lm) * 32 + kg * 8];
    }
    #pragma unroll
    for (int i = 0; i < 4; i++)
      #pragma unroll
      for (int j = 0; j < 4; j++)
        acc[i][j] = __builtin_amdgcn_mfma_f32_16x16x32_f16(af[i], bf[j], acc[i][j], 0, 0, 0);
  }

  #pragma unroll
  for (int i = 0; i < 4; i++){
    #pragma unroll
    for (int r = 0; r < 4; r++){
      int m = m0 + wm * 64 + i * 16 + kg * 4 + r;
      if (m >= M) continue;
      #pragma unroll
      for (int j = 0; j < 4; j++){
        int o = o0 + wn * 64 + j * 16 + lm;
        if (o >= O) continue;
        float v = acc[i][j][r];
        if (bias) v += bias[o];
        if (ACT == 1) v = fmaxf(v, 0.f);
        if (ACT == 2) v = fmaxf(v, 0.f) + log1pf(__expf(-fabsf(v)));
        if (ACT == 3){
          float gate = v * sigm(v);
          f16* p16 = C16 + (size_t)m * ldc16 + o;
          *p16 = (f16)((float)*p16 * gate);
        } else {
          if (W32){
            float* p = C + (size_t)m * ldc + o;
            if (ACC) v += *p;
            *p = v;
          }
          if (W16) C16[(size_t)m * ldc16 + o] = (f16)v;
        }
      }
    }
  }
}

// ---------------- depthwise causal conv (len 4) + SiLU ----------------
__global__ __launch_bounds__(256) void conv_kernel(
    const f16* __restrict__ x16, const float* __restrict__ w,
    const float* __restrict__ cb, f16* __restrict__ xi16, int dir)
{
  int idx = blockIdx.x * 256 + threadIdx.x;
  if (idx >= TT * Di) return;
  int tok = idx >> 10;
  int d   = idx & 1023;
  int n   = tok % Nn;
  const f16* base = x16 + (size_t)(tok - n) * 1024 + d;
  float acc = cb[d];
  #pragma unroll
  for (int k = 0; k < 4; k++){
    int nn = dir ? (n + 3 - k) : (n - 3 + k);
    if (nn >= 0 && nn < Nn)
      acc = fmaf(w[(d << 2) + k], (float)base[(size_t)nn * 1024], acc);
  }
  xi16[idx] = (f16)(acc * sigm(acc));
}

// ---------------- selective scan: dt in-scan, register FIFO, xi->y distinct ----------------
__global__ __launch_bounds__(256) void scan2_kernel(
    const f16* __restrict__ dbc16, const float* __restrict__ dbc,
    const f16* __restrict__ xi, f16* __restrict__ y,
    const f16* __restrict__ dtw, const float* __restrict__ dtb,
    const float* __restrict__ A_log, const float* __restrict__ Dp, int dir)
{
  int tid  = blockIdx.x * 256 + threadIdx.x;
  int g    = tid & 3;
  int chain= tid >> 2;
  int d    = chain & 1023;
  int b    = chain >> 10;
  float4 alog = *(const float4*)(A_log + (size_t)d * 16 + (g << 2));
  float Aj[4] = { -__expf(alog.x), -__expf(alog.y), -__expf(alog.z), -__expf(alog.w) };
  float Dpv  = Dp[d];
  float bias = dtb[d];
  f16x8 wdt16 = *(const f16x8*)(dtw + (size_t)d * 32 + (g << 3));
  float wdt[8];
  #pragma unroll
  for (int i = 0; i < 8; i++) wdt[i] = (float)wdt16[i];

  const int stp = dir ? -1 : 1;
  const ptrdiff_t sBC = (ptrdiff_t)stp * 64;
  const ptrdiff_t sXi = (ptrdiff_t)stp * 1024;
  size_t tok0 = (size_t)b * Nn + (dir ? Nn - 1 : 0);
  const f16*   pDt = dbc16 + tok0 * 64 + (g << 3);
  const float* pB  = dbc   + tok0 * 64 + 32 + (g << 2);
  const float* pC  = pB + 16;
  const f16*   pXi = xi + tok0 * 1024 + d;
  f16*         pY  = y  + tok0 * 1024 + d;

  float h[4] = {0.f, 0.f, 0.f, 0.f};
  f16x8  dtF[PF];
  float4 BF[PF], CF[PF];
  float  xiF[PF];

  #pragma unroll
  for (int s = 0; s < PF; s++){
    dtF[s] = *(const f16x8*)(pDt + s * sBC);
    BF[s]  = *(const float4*)(pB + s * sBC);
    CF[s]  = *(const float4*)(pC + s * sBC);
    xiF[s] = (float)pXi[s * sXi];
  }
  const f16*   lDt = pDt + PF * sBC;
  const float* lB  = pB  + PF * sBC;
  const float* lC  = pC  + PF * sBC;
  const f16*   lXi = pXi + PF * sXi;

  int t = 0;
  // hot loop: all PF refills in range (t + 2*PF <= Nn)
  for (; t + 2 * PF <= Nn; t += PF){
    #pragma unroll
    for (int s = 0; s < PF; s++){
      float dtp = 0.f;
      #pragma unroll
      for (int i = 0; i < 8; i++) dtp += (float)dtF[s][i] * wdt[i];
      dtp += __shfl_xor(dtp, 1);
      dtp += __shfl_xor(dtp, 2);
      float v  = dtp + bias;
      float dt = fmaxf(v, 0.f) + log1pf(__expf(-fabsf(v)));
      float xv = xiF[s];
      float dtx = dt * xv;
      float Br[4] = {BF[s].x, BF[s].y, BF[s].z, BF[s].w};
      float Cr[4] = {CF[s].x, CF[s].y, CF[s].z, CF[s].w};
      float yv = 0.f;
      #pragma unroll
      for (int j = 0; j < 4; j++){
        float dA = __expf(dt * Aj[j]);
        h[j] = fmaf(dA, h[j], dtx * Br[j]);
        yv = fmaf(h[j], Cr[j], yv);
      }
      yv += __shfl_xor(yv, 1);
      yv += __shfl_xor(yv, 2);
      if (g == 0) *pY = (f16)(yv + xv * Dpv);
      pY += sXi;
      // refill slot s with token t+s+PF (in range here)
      dtF[s] = *(const f16x8*)(lDt + s * sBC);
      BF[s]  = *(const float4*)(lB + s * sBC);
      CF[s]  = *(const float4*)(lC + s * sBC);
      xiF[s] = (float)lXi[s * sXi];
    }
    lDt += PF * sBC; lB += PF * sBC; lC += PF * sBC; lXi += PF * sXi;
  }
  // tail: guarded consume + guarded refill
  for (; t < Nn; t += PF){
    #pragma unroll
    for (int s = 0; s < PF; s++){
      if (t + s < Nn){
        float dtp = 0.f;
        #pragma unroll
        for (int i = 0; i < 8; i++) dtp += (float)dtF[s][i] * wdt[i];
        dtp += __shfl_xor(dtp, 1);
        dtp += __shfl_xor(dtp, 2);
        float v  = dtp + bias;
        float dt = fmaxf(v, 0.f) + log1pf(__expf(-fabsf(v)));
        float xv = xiF[s];
        float dtx = dt * xv;
        float Br[4] = {BF[s].x, BF[s].y, BF[s].z, BF[s].w};
        float Cr[4] = {CF[s].x, CF[s].y, CF[s].z, CF[s].w};
        float yv = 0.f;
        #pragma unroll
        for (int j = 0; j < 4; j++){
          float dA = __expf(dt * Aj[j]);
          h[j] = fmaf(dA, h[j], dtx * Br[j]);
          yv = fmaf(h[j], Cr[j], yv);
        }
        yv += __shfl_xor(yv, 1);
        yv += __shfl_xor(yv, 2);
        if (g == 0) *pY = (f16)(yv + xv * Dpv);
        pY += sXi;
        if (t + s + PF < Nn){
          dtF[s] = *(const f16x8*)(lDt + s * sBC);
          BF[s]  = *(const float4*)(lB + s * sBC);
          CF[s]  = *(const float4*)(lC + s * sBC);
          xiF[s] = (float)lXi[s * sXi];
        }
      }
    }
    lDt += PF * sBC; lB += PF * sBC; lC += PF * sBC; lXi += PF * sXi;
  }
}

// ---------------- (optional add) + LayerNorm; writes f32 e AND f16 e16 ----------------
__global__ __launch_bounds__(256) void add_ln_kernel(
    float* __restrict__ e, const float* __restrict__ add,
    const float* __restrict__ w, const float* __restrict__ bias,
    f16* __restrict__ e16)
{
  int wv = threadIdx.x >> 6, lane = threadIdx.x & 63;
  int tok = blockIdx.x * 4 + wv;
  float* p = e + (size_t)tok * Dm;
  float4 v0 = ((const float4*)p)[lane * 2];
  float4 v1 = ((const float4*)p)[lane * 2 + 1];
  float x[8] = {v0.x, v0.y, v0.z, v0.w, v1.x, v1.y, v1.z, v1.w};
  if (add){
    const float* q = add + (size_t)tok * Dm;
    float4 a0 = ((const float4*)q)[lane * 2];
    float4 a1 = ((const float4*)q)[lane * 2 + 1];
    x[0] += a0.x; x[1] += a0.y; x[2] += a0.z; x[3] += a0.w;
    x[4] += a1.x; x[5] += a1.y; x[6] += a1.z; x[7] += a1.w;
  }
  float s = 0.f;
  #pragma unroll
  for (int i = 0; i < 8; i++) s += x[i];
  #pragma unroll
  for (int off = 32; off; off >>= 1) s += __shfl_xor(s, off);
  float m = s * (1.f / Dm);
  float vv = 0.f;
  #pragma unroll
  for (int i = 0; i < 8; i++){ float dd = x[i] - m; vv += dd * dd; }
  #pragma unroll
  for (int off = 32; off; off >>= 1) vv += __shfl_xor(vv, off);
  float rs = rsqrtf(vv * (1.f / Dm) + EPSf);
  int db = lane * 8;
  float4 w0 = *(const float4*)(w + db),    w1 = *(const float4*)(w + db + 4);
  float4 b0 = *(const float4*)(bias + db), b1 = *(const float4*)(bias + db + 4);
  float wr[8] = {w0.x, w0.y, w0.z, w0.w, w1.x, w1.y, w1.z, w1.w};
  float br[8] = {b0.x, b0.y, b0.z, b0.w, b1.x, b1.y, b1.z, b1.w};
  float o[8];
  #pragma unroll
  for (int i = 0; i < 8; i++) o[i] = (x[i] - m) * rs * wr[i] + br[i];
  ((float4*)p)[lane * 2]     = make_float4(o[0], o[1], o[2], o[3]);
  ((float4*)p)[lane * 2 + 1] = make_float4(o[4], o[5], o[6], o[7]);
  f16x8 hv;
  #pragma unroll
  for (int i = 0; i < 8; i++) hv[i] = (f16)o[i];
  *(f16x8*)(e16 + (size_t)tok * Dm + db) = hv;
}

// ---------------- de-normalize + transpose to (B, FUT, N) ----------------
__global__ __launch_bounds__(256) void final_kernel(
    const float* __restrict__ dec, const float* __restrict__ meanb,
    const float* __restrict__ stdb, const float* __restrict__ rw,
    const float* __restrict__ rb, float* __restrict__ out)
{
  int idx = blockIdx.x * 256 + threadIdx.x;
  if (idx >= Bb * FUTc * Nn) return;
  int n  = idx % Nn;
  int bf = idx / Nn;
  int f  = bf % FUTc;
  int b  = bf / FUTc;
  int tok = b * Nn + n;
  float v = dec[(size_t)tok * FUTc + f];
  out[idx] = (v - rb[n]) / (rw[n] + 1e-10f) * stdb[tok] + meanb[tok];
}

extern "C" void kernel_launch(void* const* d_in, const int* in_sizes, int n_in,
                              void* d_out, int out_size, void* d_ws, size_t ws_size,
                              hipStream_t stream)
{
  const float* x_hist    = (const float*)d_in[0];
  const float* revin_w   = (const float*)d_in[1];
  const float* revin_b   = (const float*)d_in[2];
  const float* embed_w   = (const float*)d_in[3];
  const float* embed_b   = (const float*)d_in[4];
  const float* in_proj_w = (const float*)d_in[5];
  const float* conv_w    = (const float*)d_in[6];
  const float* conv_b    = (const float*)d_in[7];
  const float* x_proj_w  = (const float*)d_in[8];
  const float* dt_proj_w = (const float*)d_in[9];
  const float* dt_proj_b = (const float*)d_in[10];
  const float* A_log     = (const float*)d_in[11];
  const float* Dp        = (const float*)d_in[12];
  const float* out_proj_w= (const float*)d_in[13];
  const float* conv1_w   = (const float*)d_in[14];
  const float* conv1_b   = (const float*)d_in[15];
  const float* conv2_w   = (const float*)d_in[16];
  const float* conv2_b   = (const float*)d_in[17];
  const float* norm1_w   = (const float*)d_in[18];
  const float* norm1_b   = (const float*)d_in[19];
  const float* norm2_w   = (const float*)d_in[20];
  const float* norm2_b   = (const float*)d_in[21];
  const float* normf_w   = (const float*)d_in[22];
  const float* normf_b   = (const float*)d_in[23];
  const float* proj_w    = (const float*)d_in[24];
  const float* proj_b    = (const float*)d_in[25];

  // ---- workspace layout (~224 MB; known ws >= 229 MB) ----
  float* ws    = (float*)d_ws;
  float* meanb = ws;                                    // TT f32
  float* stdb  = meanb + TT;                            // TT f32
  float* e     = stdb + TT;                             // TT*512 f32
  f16*   e16   = (f16*)(e + (size_t)TT * Dm);           // TT*512 f16
  f16*   x16   = e16 + (size_t)TT * Dm;                 // TT*1024 f16 (conv in; then y out)
  f16*   xi16  = x16 + (size_t)TT * Di;                 // TT*1024 f16 (conv out / scan in)
  float* dbc   = (float*)(xi16 + (size_t)TT * Di);      // TT*64 f32
  f16*   dbc16 = (f16*)(dbc + (size_t)TT * 64);         // TT*64 f16
  f16*   ipw16 = dbc16 + (size_t)TT * 64;               // 4*2048*512
  f16*   opw16 = ipw16 + (size_t)4 * 2048 * Dm;         // 4*512*1024
  f16*   c1w16 = opw16 + (size_t)4 * Dm * Di;           // 2*512*512
  f16*   c2w16 = c1w16 + (size_t)2 * Dm * Dm;           // 2*512*512
  f16*   xpw16 = c2w16 + (size_t)2 * Dm * Dm;           // 4*64*1024
  f16*   dtw16 = xpw16 + (size_t)4 * 64 * Di;           // 4*1024*32
  f16*   emw16 = dtw16 + (size_t)4 * Di * DRr;          // 512*96
  f16*   prw16 = emw16 + (size_t)Dm * Lh;               // 96*512

  // aliases into freed regions
  f16*   xn16  = x16;               // [TT][96] embed staging (pre-loop)
  f16*   h16   = xi16;              // [TT][512] FFN hidden (post-mamba)
  float* ftmp  = (float*)x16;       // [TT][512] f32 conv2 out
  float* dec   = (float*)x16;       // [TT][96] f32 final projection

  dim3 blk(256);
  auto cvt = [&](const float* in, f16* out, size_t n){
    int n4 = (int)(n / 4);
    cvt_kernel<<<(n4 + 255) / 256, blk, 0, stream>>>(in, out, n4);
  };
  cvt(in_proj_w,  ipw16, (size_t)4 * 2048 * Dm);
  cvt(out_proj_w, opw16, (size_t)4 * Dm * Di);
  cvt(conv1_w,    c1w16, (size_t)2 * Dm * Dm);
  cvt(conv2_w,    c2w16, (size_t)2 * Dm * Dm);
  cvt(x_proj_w,   xpw16, (size_t)4 * 64 * Di);
  cvt(dt_proj_w,  dtw16, (size_t)4 * Di * DRr);
  cvt(embed_w,    emw16, (size_t)Dm * Lh);
  cvt(proj_w,     prw16, (size_t)FUTc * Dm);

  stats_kernel<<<(TT + 255) / 256, blk, 0, stream>>>(x_hist, meanb, stdb);
  prep_kernel<<<(Bb * Lh * Nn + 255) / 256, blk, 0, stream>>>(x_hist, meanb, stdb, revin_w, revin_b, xn16);

  const int gy = (TT + 127) / 128;   // 216
  // embed: [TT,96] x [512,96] -> e (f32) + e16
  gemm16_kernel<0,0,1,1><<<dim3(4, gy), blk, 0, stream>>>(
      xn16, Lh, emw16, Lh, embed_b, e, Dm, e16, Dm, Dm, TT);

  for (int l = 0; l < 2; l++){
    for (int dir = 0; dir < 2; dir++){
      int wi = l * 2 + dir;
      const f16* Wx = ipw16 + (size_t)wi * 2048 * Dm;           // rows 0..1023 (x half)
      const f16* Wz = Wx + (size_t)Di * Dm;                     // rows 1024..2047 (z half)
      // in_proj x-half: [TT,512] x [1024,512] -> x16 f16
      gemm16_kernel<0,0,0,1><<<dim3(8, gy), blk, 0, stream>>>(
          e16, Dm, Wx, Dm, nullptr, nullptr, 0, x16, Di, Di, TT);
      // depthwise conv + silu: x16 -> xi16   (x16 dead after this)
      conv_kernel<<<((size_t)TT * Di + 255) / 256, blk, 0, stream>>>(
          x16, conv_w + (size_t)wi * Di * 4, conv_b + (size_t)wi * Di, xi16, dir);
      // x_proj: [TT,1024] x [64,1024] -> dbc f32 + dbc16 f16
      gemm16_kernel<0,0,1,1><<<dim3(1, gy), blk, 0, stream>>>(
          xi16, Di, xpw16 + (size_t)wi * 64 * Di, Di, nullptr,
          dbc, 64, dbc16, 64, 64, TT);
      // scan: reads xi16, writes ungated y -> x16 (distinct buffers)
      scan2_kernel<<<Bb * 16, blk, 0, stream>>>(
          dbc16, dbc, xi16, x16,
          dtw16 + (size_t)wi * Di * DRr, dt_proj_b + (size_t)wi * Di,
          A_log + (size_t)wi * Di * Ds, Dp + (size_t)wi * Di, dir);
      // gate: y(x16) *= silu(e16 @ Wz^T)   (f16 RMW epilogue)
      gemm16_kernel<3,0,0,1><<<dim3(8, gy), blk, 0, stream>>>(
          e16, Dm, Wz, Dm, nullptr, nullptr, 0, x16, Di, Di, TT);
      // out_proj: [TT,1024] x [512,1024] -> e += (residual accumulate)
      gemm16_kernel<0,1,1,0><<<dim3(4, gy), blk, 0, stream>>>(
          x16, Di, opw16 + (size_t)wi * Dm * Di, Di, nullptr,
          e, Dm, nullptr, 0, Dm, TT);
    }
    // e = LN(e) (mf+mr already accumulated); regenerate e16
    add_ln_kernel<<<TT / 4, blk, 0, stream>>>(e, nullptr, norm1_w + l * Dm, norm1_b + l * Dm, e16);
    // FFN: conv1 relu -> h16 (aliases xi16)
    gemm16_kernel<1,0,0,1><<<dim3(4, gy), blk, 0, stream>>>(
        e16, Dm, c1w16 + (size_t)l * Dm * Dm, Dm, conv1_b + l * Dm,
        nullptr, 0, h16, Dm, Dm, TT);
    // conv2 -> ftmp f32 (aliases x16)
    gemm16_kernel<0,0,1,0><<<dim3(4, gy), blk, 0, stream>>>(
        h16, Dm, c2w16 + (size_t)l * Dm * Dm, Dm, conv2_b + l * Dm,
        ftmp, Dm, nullptr, 0, Dm, TT);
    add_ln_kernel<<<TT / 4, blk, 0, stream>>>(e, ftmp, norm2_w + l * Dm, norm2_b + l * Dm, e16);
  }

  add_ln_kernel<<<TT / 4, blk, 0, stream>>>(e, nullptr, normf_w, normf_b, e16);
  // proj: [TT,512] x [96,512] -> dec f32
  gemm16_kernel<0,0,1,0><<<dim3(1, gy), blk, 0, stream>>>(
      e16, Dm, prw16, Dm, proj_b, dec, FUTc, nullptr, 0, FUTc, TT);
  final_kernel<<<(Bb * FUTc * Nn + 255) / 256, blk, 0, stream>>>(
      dec, meanb, stdb, revin_w, revin_b, (float*)d_out);
}

// Round 4
// 3356.310 us; speedup vs baseline: 4.7788x; 1.3497x over previous
//
#include <hip/hip_runtime.h>

// SDMamba forward. All GEMMs on MFMA f16 (fp32 accumulate); conv/scan/LN fp32 math.
// Full-batch; one scan per (layer,dir). Scan: double-banked register FIFO (PF=4/bank)
// with compiler fences so loads issue a full bank ahead; launch_bounds(256,2) to
// allow ~200 VGPRs (grid gives only 2 waves/SIMD, so no occupancy loss).

typedef _Float16 f16;
typedef _Float16 f16x8 __attribute__((ext_vector_type(8)));
typedef _Float16 f16x4 __attribute__((ext_vector_type(4)));
typedef float    f32x4 __attribute__((ext_vector_type(4)));

constexpr int Bb  = 32;
constexpr int Lh  = 96;
constexpr int FUTc= 96;
constexpr int Nn  = 862;
constexpr int Dm  = 512;
constexpr int Ds  = 16;
constexpr int Di  = 1024;
constexpr int DRr = 32;
constexpr int TT  = Bb * Nn;     // 27584
constexpr float EPSf = 1e-5f;
constexpr int PF = 4;            // scan FIFO slots per bank (2 banks)

__device__ __forceinline__ float sigm(float x){ return 1.f / (1.f + __expf(-x)); }

__device__ __forceinline__ void gll16(f16* lds, const f16* g){
  __builtin_amdgcn_global_load_lds(
      (const __attribute__((address_space(1))) void*)g,
      (__attribute__((address_space(3)))       void*)lds, 16, 0, 0);
}

// ---------------- RevIN stats ----------------
__global__ __launch_bounds__(256) void stats_kernel(const float* __restrict__ x,
    float* __restrict__ meanb, float* __restrict__ stdb)
{
  int i = blockIdx.x * 256 + threadIdx.x;
  if (i >= TT) return;
  int b = i / Nn, n = i - b * Nn;
  const float* p = x + (size_t)b * Lh * Nn + n;
  float s = 0.f, sq = 0.f;
  #pragma unroll 4
  for (int l = 0; l < Lh; l++){ float v = p[(size_t)l * Nn]; s += v; sq += v * v; }
  float m = s * (1.f / Lh);
  float var = sq * (1.f / Lh) - m * m;
  meanb[i] = m;
  stdb[i]  = sqrtf(var + EPSf);
}

// ---------------- normalize + layout to [tok][L] fp16 ----------------
__global__ __launch_bounds__(256) void prep_kernel(const float* __restrict__ x,
    const float* __restrict__ meanb, const float* __restrict__ stdb,
    const float* __restrict__ rw, const float* __restrict__ rb,
    f16* __restrict__ xn16)
{
  int idx = blockIdx.x * 256 + threadIdx.x;
  if (idx >= Bb * Lh * Nn) return;
  int n  = idx % Nn;
  int bl = idx / Nn;
  int l  = bl % Lh;
  int b  = bl / Lh;
  int tok = b * Nn + n;
  float v = x[idx];
  xn16[(size_t)tok * Lh + l] = (f16)((v - meanb[tok]) / stdb[tok] * rw[n] + rb[n]);
}

// ---------------- f32 -> f16 convert ----------------
__global__ __launch_bounds__(256) void cvt_kernel(const float* __restrict__ in,
    f16* __restrict__ out, int n4)
{
  int i = blockIdx.x * 256 + threadIdx.x;
  if (i >= n4) return;
  float4 v = ((const float4*)in)[i];
  f16x4 h; h[0] = (f16)v.x; h[1] = (f16)v.y; h[2] = (f16)v.z; h[3] = (f16)v.w;
  *(f16x4*)(out + (size_t)i * 4) = h;
}

// ---------------- MFMA GEMM: C[m,o] = act(sum_k A[m,k]*W[o,k] + bias[o]) ----------------
// ACT: 0 none, 1 relu, 2 softplus, 3 silu-gate-RMW on C16 (C16 *= silu(v)).
// ACC: C += (W32 path). W32/W16: write f32 C / f16 C16.
template<int ACT, int ACC, int W32, int W16>
__global__ __launch_bounds__(256) void gemm16_kernel(
    const f16* __restrict__ A, int lda,
    const f16* __restrict__ W, int K,
    const float* __restrict__ bias,
    float* __restrict__ C, int ldc,
    f16* __restrict__ C16, int ldc16,
    int O, int M)
{
  __shared__ f16 As[128 * 32];
  __shared__ f16 Bs[128 * 32];
  const int tid  = threadIdx.x;
  const int lane = tid & 63;
  const int w    = tid >> 6;
  const int wm   = w >> 1, wn = w & 1;
  const int m0   = blockIdx.y * 128, o0 = blockIdx.x * 128;
  const int lm   = lane & 15, kg = lane >> 4;
  const int sr0  = w * 32 + (lane >> 2);
  const int sc   = (lane & 3) << 3;

  f32x4 acc[4][4];
  #pragma unroll
  for (int i = 0; i < 4; i++)
    #pragma unroll
    for (int j = 0; j < 4; j++){ f32x4 z = {0.f,0.f,0.f,0.f}; acc[i][j] = z; }

  for (int k0 = 0; k0 < K; k0 += 32){
    __syncthreads();
    {
      int r0 = min(m0 + sr0,      M - 1);
      int r1 = min(m0 + sr0 + 16, M - 1);
      gll16(&As[w * 1024],       A + (size_t)r0 * lda + k0 + sc);
      gll16(&As[w * 1024 + 512], A + (size_t)r1 * lda + k0 + sc);
      int q0 = min(o0 + sr0,      O - 1);
      int q1 = min(o0 + sr0 + 16, O - 1);
      gll16(&Bs[w * 1024],       W + (size_t)q0 * K + k0 + sc);
      gll16(&Bs[w * 1024 + 512], W + (size_t)q1 * K + k0 + sc);
    }
    __syncthreads();
    f16x8 af[4], bf[4];
    #pragma unroll
    for (int f = 0; f < 4; f++){
      af[f] = *(const f16x8*)&As[(wm * 64 + f * 16 + lm) * 32 + kg * 8];
      bf[f] = *(const f16x8*)&Bs[(wn * 64 + f * 16 + lm) * 32 + kg * 8];
    }
    #pragma unroll
    for (int i = 0; i < 4; i++)
      #pragma unroll
      for (int j = 0; j < 4; j++)
        acc[i][j] = __builtin_amdgcn_mfma_f32_16x16x32_f16(af[i], bf[j], acc[i][j], 0, 0, 0);
  }

  #pragma unroll
  for (int i = 0; i < 4; i++){
    #pragma unroll
    for (int r = 0; r < 4; r++){
      int m = m0 + wm * 64 + i * 16 + kg * 4 + r;
      if (m >= M) continue;
      #pragma unroll
      for (int j = 0; j < 4; j++){
        int o = o0 + wn * 64 + j * 16 + lm;
        if (o >= O) continue;
        float v = acc[i][j][r];
        if (bias) v += bias[o];
        if (ACT == 1) v = fmaxf(v, 0.f);
        if (ACT == 2) v = fmaxf(v, 0.f) + log1pf(__expf(-fabsf(v)));
        if (ACT == 3){
          float gate = v * sigm(v);
          f16* p16 = C16 + (size_t)m * ldc16 + o;
          *p16 = (f16)((float)*p16 * gate);
        } else {
          if (W32){
            float* p = C + (size_t)m * ldc + o;
            if (ACC) v += *p;
            *p = v;
          }
          if (W16) C16[(size_t)m * ldc16 + o] = (f16)v;
        }
      }
    }
  }
}

// ---------------- depthwise causal conv (len 4) + SiLU ----------------
__global__ __launch_bounds__(256) void conv_kernel(
    const f16* __restrict__ x16, const float* __restrict__ w,
    const float* __restrict__ cb, f16* __restrict__ xi16, int dir)
{
  int idx = blockIdx.x * 256 + threadIdx.x;
  if (idx >= TT * Di) return;
  int tok = idx >> 10;
  int d   = idx & 1023;
  int n   = tok % Nn;
  const f16* base = x16 + (size_t)(tok - n) * 1024 + d;
  float acc = cb[d];
  #pragma unroll
  for (int k = 0; k < 4; k++){
    int nn = dir ? (n + 3 - k) : (n - 3 + k);
    if (nn >= 0 && nn < Nn)
      acc = fmaf(w[(d << 2) + k], (float)base[(size_t)nn * 1024], acc);
  }
  xi16[idx] = (f16)(acc * sigm(acc));
}

// ---------------- selective scan: double-banked register FIFO ----------------
__global__ __launch_bounds__(256, 2) void scan3_kernel(
    const f16* __restrict__ dbc16, const float* __restrict__ dbc,
    const f16* __restrict__ xi, f16* __restrict__ y,
    const f16* __restrict__ dtw, const float* __restrict__ dtb,
    const float* __restrict__ A_log, const float* __restrict__ Dp, int dir)
{
  int tid  = blockIdx.x * 256 + threadIdx.x;
  int g    = tid & 3;
  int chain= tid >> 2;
  int d    = chain & 1023;
  int b    = chain >> 10;
  float4 alog = *(const float4*)(A_log + (size_t)d * 16 + (g << 2));
  float Aj[4] = { -__expf(alog.x), -__expf(alog.y), -__expf(alog.z), -__expf(alog.w) };
  float Dpv  = Dp[d];
  float bias = dtb[d];
  f16x8 wdt16 = *(const f16x8*)(dtw + (size_t)d * 32 + (g << 3));
  float wdt[8];
  #pragma unroll
  for (int i = 0; i < 8; i++) wdt[i] = (float)wdt16[i];

  const int stp = dir ? -1 : 1;
  const ptrdiff_t sBC = (ptrdiff_t)stp * 64;
  const ptrdiff_t sXi = (ptrdiff_t)stp * 1024;
  size_t tok0 = (size_t)b * Nn + (dir ? Nn - 1 : 0);
  // load cursors (walk forward) + y cursor
  const f16*   lDt = dbc16 + tok0 * 64 + (g << 3);
  const float* lB  = dbc   + tok0 * 64 + 32 + (g << 2);
  const float* lC  = lB + 16;
  const f16*   lXi = xi + tok0 * 1024 + d;
  f16*         pY  = y  + tok0 * 1024 + d;

  float h[4] = {0.f, 0.f, 0.f, 0.f};

  f16x8  dtA[PF], dtB[PF];
  float4 BA[PF],  BB[PF];
  float4 CA[PF],  CB[PF];
  float  xA[PF],  xB[PF];

  auto loadblk = [&](f16x8* dtF, float4* BF, float4* CF, float* xF){
    #pragma unroll
    for (int s = 0; s < PF; s++){
      dtF[s] = *(const f16x8*)(lDt + s * sBC);
      BF[s]  = *(const float4*)(lB + s * sBC);
      CF[s]  = *(const float4*)(lC + s * sBC);
      xF[s]  = (float)lXi[s * sXi];
    }
    lDt += PF * sBC; lB += PF * sBC; lC += PF * sBC; lXi += PF * sXi;
  };

  auto step = [&](const f16x8& dtv, const float4& Bv, const float4& Cv, float xv){
    float dtp = 0.f;
    #pragma unroll
    for (int i = 0; i < 8; i++) dtp += (float)dtv[i] * wdt[i];
    dtp += __shfl_xor(dtp, 1);
    dtp += __shfl_xor(dtp, 2);
    float v  = dtp + bias;
    float dt = fmaxf(v, 0.f) + __logf(1.f + __expf(-fabsf(v)));
    float dtx = dt * xv;
    float Br[4] = {Bv.x, Bv.y, Bv.z, Bv.w};
    float Cr[4] = {Cv.x, Cv.y, Cv.z, Cv.w};
    float yv = 0.f;
    #pragma unroll
    for (int j = 0; j < 4; j++){
      float dA = __expf(dt * Aj[j]);
      h[j] = fmaf(dA, h[j], dtx * Br[j]);
      yv = fmaf(h[j], Cr[j], yv);
    }
    yv += __shfl_xor(yv, 1);
    yv += __shfl_xor(yv, 2);
    if (g == 0) *pY = (f16)(yv + xv * Dpv);
    pY += sXi;
  };

  loadblk(dtA, BA, CA, xA);          // tokens [0, PF)
  int t = 0;
  for (; t + 3 * PF <= Nn; t += 2 * PF){
    loadblk(dtB, BB, CB, xB);        // [t+PF, t+2PF)
    asm volatile("" ::: "memory");   // pin: B-loads issue before compute(A)
    #pragma unroll
    for (int s = 0; s < PF; s++) step(dtA[s], BA[s], CA[s], xA[s]);
    loadblk(dtA, BA, CA, xA);        // [t+2PF, t+3PF)
    asm volatile("" ::: "memory");
    #pragma unroll
    for (int s = 0; s < PF; s++) step(dtB[s], BB[s], CB[s], xB[s]);
  }
  // tail: bank A holds [t, t+PF), cursors point at token t+PF
  int rem = Nn - t;
  #pragma unroll
  for (int s = 0; s < PF; s++)
    if (s < rem) step(dtA[s], BA[s], CA[s], xA[s]);
  for (int tt = t + PF; tt < Nn; tt++){
    f16x8  dv = *(const f16x8*)lDt;
    float4 Bv = *(const float4*)lB;
    float4 Cv = *(const float4*)lC;
    float  xv = (float)*lXi;
    step(dv, Bv, Cv, xv);
    lDt += sBC; lB += sBC; lC += sBC; lXi += sXi;
  }
}

// ---------------- (optional add) + LayerNorm; writes f32 e AND f16 e16 ----------------
__global__ __launch_bounds__(256) void add_ln_kernel(
    float* __restrict__ e, const float* __restrict__ add,
    const float* __restrict__ w, const float* __restrict__ bias,
    f16* __restrict__ e16)
{
  int wv = threadIdx.x >> 6, lane = threadIdx.x & 63;
  int tok = blockIdx.x * 4 + wv;
  float* p = e + (size_t)tok * Dm;
  float4 v0 = ((const float4*)p)[lane * 2];
  float4 v1 = ((const float4*)p)[lane * 2 + 1];
  float x[8] = {v0.x, v0.y, v0.z, v0.w, v1.x, v1.y, v1.z, v1.w};
  if (add){
    const float* q = add + (size_t)tok * Dm;
    float4 a0 = ((const float4*)q)[lane * 2];
    float4 a1 = ((const float4*)q)[lane * 2 + 1];
    x[0] += a0.x; x[1] += a0.y; x[2] += a0.z; x[3] += a0.w;
    x[4] += a1.x; x[5] += a1.y; x[6] += a1.z; x[7] += a1.w;
  }
  float s = 0.f;
  #pragma unroll
  for (int i = 0; i < 8; i++) s += x[i];
  #pragma unroll
  for (int off = 32; off; off >>= 1) s += __shfl_xor(s, off);
  float m = s * (1.f / Dm);
  float vv = 0.f;
  #pragma unroll
  for (int i = 0; i < 8; i++){ float dd = x[i] - m; vv += dd * dd; }
  #pragma unroll
  for (int off = 32; off; off >>= 1) vv += __shfl_xor(vv, off);
  float rs = rsqrtf(vv * (1.f / Dm) + EPSf);
  int db = lane * 8;
  float4 w0 = *(const float4*)(w + db),    w1 = *(const float4*)(w + db + 4);
  float4 b0 = *(const float4*)(bias + db), b1 = *(const float4*)(bias + db + 4);
  float wr[8] = {w0.x, w0.y, w0.z, w0.w, w1.x, w1.y, w1.z, w1.w};
  float br[8] = {b0.x, b0.y, b0.z, b0.w, b1.x, b1.y, b1.z, b1.w};
  float o[8];
  #pragma unroll
  for (int i = 0; i < 8; i++) o[i] = (x[i] - m) * rs * wr[i] + br[i];
  ((float4*)p)[lane * 2]     = make_float4(o[0], o[1], o[2], o[3]);
  ((float4*)p)[lane * 2 + 1] = make_float4(o[4], o[5], o[6], o[7]);
  f16x8 hv;
  #pragma unroll
  for (int i = 0; i < 8; i++) hv[i] = (f16)o[i];
  *(f16x8*)(e16 + (size_t)tok * Dm + db) = hv;
}

// ---------------- de-normalize + transpose to (B, FUT, N) ----------------
__global__ __launch_bounds__(256) void final_kernel(
    const float* __restrict__ dec, const float* __restrict__ meanb,
    const float* __restrict__ stdb, const float* __restrict__ rw,
    const float* __restrict__ rb, float* __restrict__ out)
{
  int idx = blockIdx.x * 256 + threadIdx.x;
  if (idx >= Bb * FUTc * Nn) return;
  int n  = idx % Nn;
  int bf = idx / Nn;
  int f  = bf % FUTc;
  int b  = bf / FUTc;
  int tok = b * Nn + n;
  float v = dec[(size_t)tok * FUTc + f];
  out[idx] = (v - rb[n]) / (rw[n] + 1e-10f) * stdb[tok] + meanb[tok];
}

extern "C" void kernel_launch(void* const* d_in, const int* in_sizes, int n_in,
                              void* d_out, int out_size, void* d_ws, size_t ws_size,
                              hipStream_t stream)
{
  const float* x_hist    = (const float*)d_in[0];
  const float* revin_w   = (const float*)d_in[1];
  const float* revin_b   = (const float*)d_in[2];
  const float* embed_w   = (const float*)d_in[3];
  const float* embed_b   = (const float*)d_in[4];
  const float* in_proj_w = (const float*)d_in[5];
  const float* conv_w    = (const float*)d_in[6];
  const float* conv_b    = (const float*)d_in[7];
  const float* x_proj_w  = (const float*)d_in[8];
  const float* dt_proj_w = (const float*)d_in[9];
  const float* dt_proj_b = (const float*)d_in[10];
  const float* A_log     = (const float*)d_in[11];
  const float* Dp        = (const float*)d_in[12];
  const float* out_proj_w= (const float*)d_in[13];
  const float* conv1_w   = (const float*)d_in[14];
  const float* conv1_b   = (const float*)d_in[15];
  const float* conv2_w   = (const float*)d_in[16];
  const float* conv2_b   = (const float*)d_in[17];
  const float* norm1_w   = (const float*)d_in[18];
  const float* norm1_b   = (const float*)d_in[19];
  const float* norm2_w   = (const float*)d_in[20];
  const float* norm2_b   = (const float*)d_in[21];
  const float* normf_w   = (const float*)d_in[22];
  const float* normf_b   = (const float*)d_in[23];
  const float* proj_w    = (const float*)d_in[24];
  const float* proj_b    = (const float*)d_in[25];

  // ---- workspace layout (~224 MB; known ws >= 226 MB) ----
  float* ws    = (float*)d_ws;
  float* meanb = ws;                                    // TT f32
  float* stdb  = meanb + TT;                            // TT f32
  float* e     = stdb + TT;                             // TT*512 f32
  f16*   e16   = (f16*)(e + (size_t)TT * Dm);           // TT*512 f16
  f16*   x16   = e16 + (size_t)TT * Dm;                 // TT*1024 f16 (conv in; then y out)
  f16*   xi16  = x16 + (size_t)TT * Di;                 // TT*1024 f16 (conv out / scan in)
  float* dbc   = (float*)(xi16 + (size_t)TT * Di);      // TT*64 f32
  f16*   dbc16 = (f16*)(dbc + (size_t)TT * 64);         // TT*64 f16
  f16*   ipw16 = dbc16 + (size_t)TT * 64;               // 4*2048*512
  f16*   opw16 = ipw16 + (size_t)4 * 2048 * Dm;         // 4*512*1024
  f16*   c1w16 = opw16 + (size_t)4 * Dm * Di;           // 2*512*512
  f16*   c2w16 = c1w16 + (size_t)2 * Dm * Dm;           // 2*512*512
  f16*   xpw16 = c2w16 + (size_t)2 * Dm * Dm;           // 4*64*1024
  f16*   dtw16 = xpw16 + (size_t)4 * 64 * Di;           // 4*1024*32
  f16*   emw16 = dtw16 + (size_t)4 * Di * DRr;          // 512*96
  f16*   prw16 = emw16 + (size_t)Dm * Lh;               // 96*512

  // aliases into freed regions
  f16*   xn16  = x16;               // [TT][96] embed staging (pre-loop)
  f16*   h16   = xi16;              // [TT][512] FFN hidden (post-mamba)
  float* ftmp  = (float*)x16;       // [TT][512] f32 conv2 out
  float* dec   = (float*)x16;       // [TT][96] f32 final projection

  dim3 blk(256);
  auto cvt = [&](const float* in, f16* out, size_t n){
    int n4 = (int)(n / 4);
    cvt_kernel<<<(n4 + 255) / 256, blk, 0, stream>>>(in, out, n4);
  };
  cvt(in_proj_w,  ipw16, (size_t)4 * 2048 * Dm);
  cvt(out_proj_w, opw16, (size_t)4 * Dm * Di);
  cvt(conv1_w,    c1w16, (size_t)2 * Dm * Dm);
  cvt(conv2_w,    c2w16, (size_t)2 * Dm * Dm);
  cvt(x_proj_w,   xpw16, (size_t)4 * 64 * Di);
  cvt(dt_proj_w,  dtw16, (size_t)4 * Di * DRr);
  cvt(embed_w,    emw16, (size_t)Dm * Lh);
  cvt(proj_w,     prw16, (size_t)FUTc * Dm);

  stats_kernel<<<(TT + 255) / 256, blk, 0, stream>>>(x_hist, meanb, stdb);
  prep_kernel<<<(Bb * Lh * Nn + 255) / 256, blk, 0, stream>>>(x_hist, meanb, stdb, revin_w, revin_b, xn16);

  const int gy = (TT + 127) / 128;   // 216
  // embed: [TT,96] x [512,96] -> e (f32) + e16
  gemm16_kernel<0,0,1,1><<<dim3(4, gy), blk, 0, stream>>>(
      xn16, Lh, emw16, Lh, embed_b, e, Dm, e16, Dm, Dm, TT);

  for (int l = 0; l < 2; l++){
    for (int dir = 0; dir < 2; dir++){
      int wi = l * 2 + dir;
      const f16* Wx = ipw16 + (size_t)wi * 2048 * Dm;           // rows 0..1023 (x half)
      const f16* Wz = Wx + (size_t)Di * Dm;                     // rows 1024..2047 (z half)
      // in_proj x-half: [TT,512] x [1024,512] -> x16 f16
      gemm16_kernel<0,0,0,1><<<dim3(8, gy), blk, 0, stream>>>(
          e16, Dm, Wx, Dm, nullptr, nullptr, 0, x16, Di, Di, TT);
      // depthwise conv + silu: x16 -> xi16   (x16 dead after this)
      conv_kernel<<<((size_t)TT * Di + 255) / 256, blk, 0, stream>>>(
          x16, conv_w + (size_t)wi * Di * 4, conv_b + (size_t)wi * Di, xi16, dir);
      // x_proj: [TT,1024] x [64,1024] -> dbc f32 + dbc16 f16
      gemm16_kernel<0,0,1,1><<<dim3(1, gy), blk, 0, stream>>>(
          xi16, Di, xpw16 + (size_t)wi * 64 * Di, Di, nullptr,
          dbc, 64, dbc16, 64, 64, TT);
      // scan: reads xi16, writes ungated y -> x16 (distinct buffers)
      scan3_kernel<<<Bb * 16, blk, 0, stream>>>(
          dbc16, dbc, xi16, x16,
          dtw16 + (size_t)wi * Di * DRr, dt_proj_b + (size_t)wi * Di,
          A_log + (size_t)wi * Di * Ds, Dp + (size_t)wi * Di, dir);
      // gate: y(x16) *= silu(e16 @ Wz^T)   (f16 RMW epilogue)
      gemm16_kernel<3,0,0,1><<<dim3(8, gy), blk, 0, stream>>>(
          e16, Dm, Wz, Dm, nullptr, nullptr, 0, x16, Di, Di, TT);
      // out_proj: [TT,1024] x [512,1024] -> e += (residual accumulate)
      gemm16_kernel<0,1,1,0><<<dim3(4, gy), blk, 0, stream>>>(
          x16, Di, opw16 + (size_t)wi * Dm * Di, Di, nullptr,
          e, Dm, nullptr, 0, Dm, TT);
    }
    // e = LN(e) (mf+mr already accumulated); regenerate e16
    add_ln_kernel<<<TT / 4, blk, 0, stream>>>(e, nullptr, norm1_w + l * Dm, norm1_b + l * Dm, e16);
    // FFN: conv1 relu -> h16 (aliases xi16)
    gemm16_kernel<1,0,0,1><<<dim3(4, gy), blk, 0, stream>>>(
        e16, Dm, c1w16 + (size_t)l * Dm * Dm, Dm, conv1_b + l * Dm,
        nullptr, 0, h16, Dm, Dm, TT);
    // conv2 -> ftmp f32 (aliases x16)
    gemm16_kernel<0,0,1,0><<<dim3(4, gy), blk, 0, stream>>>(
        h16, Dm, c2w16 + (size_t)l * Dm * Dm, Dm, conv2_b + l * Dm,
        ftmp, Dm, nullptr, 0, Dm, TT);
    add_ln_kernel<<<TT / 4, blk, 0, stream>>>(e, ftmp, norm2_w + l * Dm, norm2_b + l * Dm, e16);
  }

  add_ln_kernel<<<TT / 4, blk, 0, stream>>>(e, nullptr, normf_w, normf_b, e16);
  // proj: [TT,512] x [96,512] -> dec f32
  gemm16_kernel<0,0,1,0><<<dim3(1, gy), blk, 0, stream>>>(
      e16, Dm, prw16, Dm, proj_b, dec, FUTc, nullptr, 0, FUTc, TT);
  final_kernel<<<(Bb * FUTc * Nn + 255) / 256, blk, 0, stream>>>(
      dec, meanb, stdb, revin_w, revin_b, (float*)d_out);
}

// Round 5
// 3267.172 us; speedup vs baseline: 4.9092x; 1.0273x over previous
//
#include <hip/hip_runtime.h>

// SDMamba forward. All GEMMs on MFMA f16 (fp32 accumulate); conv/scan/LN fp32 math.
// Full-batch; one scan per (layer,dir). dt computed by GEMM (+softplus) into x16;
// scan reads dt/B/C/xi with a double-banked register FIFO and writes y over dt
// in place (loads issue a bank ahead of stores). B/C stay f32 (broadcast reads).

typedef _Float16 f16;
typedef _Float16 f16x8 __attribute__((ext_vector_type(8)));
typedef _Float16 f16x4 __attribute__((ext_vector_type(4)));
typedef float    f32x4 __attribute__((ext_vector_type(4)));

constexpr int Bb  = 32;
constexpr int Lh  = 96;
constexpr int FUTc= 96;
constexpr int Nn  = 862;
constexpr int Dm  = 512;
constexpr int Ds  = 16;
constexpr int Di  = 1024;
constexpr int DRr = 32;
constexpr int TT  = Bb * Nn;     // 27584
constexpr float EPSf = 1e-5f;
constexpr int PF = 4;            // scan FIFO slots per bank (2 banks)

__device__ __forceinline__ float sigm(float x){ return 1.f / (1.f + __expf(-x)); }

__device__ __forceinline__ void gll16(f16* lds, const f16* g){
  __builtin_amdgcn_global_load_lds(
      (const __attribute__((address_space(1))) void*)g,
      (__attribute__((address_space(3)))       void*)lds, 16, 0, 0);
}

// ---------------- RevIN stats ----------------
__global__ __launch_bounds__(256) void stats_kernel(const float* __restrict__ x,
    float* __restrict__ meanb, float* __restrict__ stdb)
{
  int i = blockIdx.x * 256 + threadIdx.x;
  if (i >= TT) return;
  int b = i / Nn, n = i - b * Nn;
  const float* p = x + (size_t)b * Lh * Nn + n;
  float s = 0.f, sq = 0.f;
  #pragma unroll 4
  for (int l = 0; l < Lh; l++){ float v = p[(size_t)l * Nn]; s += v; sq += v * v; }
  float m = s * (1.f / Lh);
  float var = sq * (1.f / Lh) - m * m;
  meanb[i] = m;
  stdb[i]  = sqrtf(var + EPSf);
}

// ---------------- normalize + layout to [tok][L] fp16 ----------------
__global__ __launch_bounds__(256) void prep_kernel(const float* __restrict__ x,
    const float* __restrict__ meanb, const float* __restrict__ stdb,
    const float* __restrict__ rw, const float* __restrict__ rb,
    f16* __restrict__ xn16)
{
  int idx = blockIdx.x * 256 + threadIdx.x;
  if (idx >= Bb * Lh * Nn) return;
  int n  = idx % Nn;
  int bl = idx / Nn;
  int l  = bl % Lh;
  int b  = bl / Lh;
  int tok = b * Nn + n;
  float v = x[idx];
  xn16[(size_t)tok * Lh + l] = (f16)((v - meanb[tok]) / stdb[tok] * rw[n] + rb[n]);
}

// ---------------- f32 -> f16 convert ----------------
__global__ __launch_bounds__(256) void cvt_kernel(const float* __restrict__ in,
    f16* __restrict__ out, int n4)
{
  int i = blockIdx.x * 256 + threadIdx.x;
  if (i >= n4) return;
  float4 v = ((const float4*)in)[i];
  f16x4 h; h[0] = (f16)v.x; h[1] = (f16)v.y; h[2] = (f16)v.z; h[3] = (f16)v.w;
  *(f16x4*)(out + (size_t)i * 4) = h;
}

// ---------------- MFMA GEMM: C[m,o] = act(sum_k A[m,k]*W[o,k] + bias[o]) ----------------
// ACT: 0 none, 1 relu, 2 softplus, 3 silu-gate-RMW on C16 (C16 *= silu(v)).
// ACC: C += (W32 path). W32/W16: write f32 C / f16 C16.
template<int ACT, int ACC, int W32, int W16>
__global__ __launch_bounds__(256) void gemm16_kernel(
    const f16* __restrict__ A, int lda,
    const f16* __restrict__ W, int K,
    const float* __restrict__ bias,
    float* __restrict__ C, int ldc,
    f16* __restrict__ C16, int ldc16,
    int O, int M)
{
  __shared__ f16 As[128 * 32];
  __shared__ f16 Bs[128 * 32];
  const int tid  = threadIdx.x;
  const int lane = tid & 63;
  const int w    = tid >> 6;
  const int wm   = w >> 1, wn = w & 1;
  const int m0   = blockIdx.y * 128, o0 = blockIdx.x * 128;
  const int lm   = lane & 15, kg = lane >> 4;
  const int sr0  = w * 32 + (lane >> 2);
  const int sc   = (lane & 3) << 3;

  f32x4 acc[4][4];
  #pragma unroll
  for (int i = 0; i < 4; i++)
    #pragma unroll
    for (int j = 0; j < 4; j++){ f32x4 z = {0.f,0.f,0.f,0.f}; acc[i][j] = z; }

  for (int k0 = 0; k0 < K; k0 += 32){
    __syncthreads();
    {
      int r0 = min(m0 + sr0,      M - 1);
      int r1 = min(m0 + sr0 + 16, M - 1);
      gll16(&As[w * 1024],       A + (size_t)r0 * lda + k0 + sc);
      gll16(&As[w * 1024 + 512], A + (size_t)r1 * lda + k0 + sc);
      int q0 = min(o0 + sr0,      O - 1);
      int q1 = min(o0 + sr0 + 16, O - 1);
      gll16(&Bs[w * 1024],       W + (size_t)q0 * K + k0 + sc);
      gll16(&Bs[w * 1024 + 512], W + (size_t)q1 * K + k0 + sc);
    }
    __syncthreads();
    f16x8 af[4], bf[4];
    #pragma unroll
    for (int f = 0; f < 4; f++){
      af[f] = *(const f16x8*)&As[(wm * 64 + f * 16 + lm) * 32 + kg * 8];
      bf[f] = *(const f16x8*)&Bs[(wn * 64 + f * 16 + lm) * 32 + kg * 8];
    }
    #pragma unroll
    for (int i = 0; i < 4; i++)
      #pragma unroll
      for (int j = 0; j < 4; j++)
        acc[i][j] = __builtin_amdgcn_mfma_f32_16x16x32_f16(af[i], bf[j], acc[i][j], 0, 0, 0);
  }

  #pragma unroll
  for (int i = 0; i < 4; i++){
    #pragma unroll
    for (int r = 0; r < 4; r++){
      int m = m0 + wm * 64 + i * 16 + kg * 4 + r;
      if (m >= M) continue;
      #pragma unroll
      for (int j = 0; j < 4; j++){
        int o = o0 + wn * 64 + j * 16 + lm;
        if (o >= O) continue;
        float v = acc[i][j][r];
        if (bias) v += bias[o];
        if (ACT == 1) v = fmaxf(v, 0.f);
        if (ACT == 2) v = fmaxf(v, 0.f) + log1pf(__expf(-fabsf(v)));
        if (ACT == 3){
          float gate = v * sigm(v);
          f16* p16 = C16 + (size_t)m * ldc16 + o;
          *p16 = (f16)((float)*p16 * gate);
        } else {
          if (W32){
            float* p = C + (size_t)m * ldc + o;
            if (ACC) v += *p;
            *p = v;
          }
          if (W16) C16[(size_t)m * ldc16 + o] = (f16)v;
        }
      }
    }
  }
}

// ---------------- depthwise causal conv (len 4) + SiLU, 8 channels/thread ----------------
__global__ __launch_bounds__(256) void conv_kernel(
    const f16* __restrict__ x16, const float* __restrict__ w,
    const float* __restrict__ cb, f16* __restrict__ xi16, int dir)
{
  int idx = blockIdx.x * 256 + threadIdx.x;
  if (idx >= TT * Di / 8) return;
  int tok = idx >> 7;
  int d8  = (idx & 127) << 3;
  int n   = tok % Nn;
  const f16* base = x16 + (size_t)(tok - n) * 1024 + d8;
  float4 c0 = *(const float4*)(cb + d8);
  float4 c1 = *(const float4*)(cb + d8 + 4);
  float acc[8] = {c0.x, c0.y, c0.z, c0.w, c1.x, c1.y, c1.z, c1.w};
  float wr[8][4];
  #pragma unroll
  for (int i = 0; i < 8; i++){
    float4 wv = *(const float4*)(w + (size_t)(d8 + i) * 4);
    wr[i][0] = wv.x; wr[i][1] = wv.y; wr[i][2] = wv.z; wr[i][3] = wv.w;
  }
  #pragma unroll
  for (int k = 0; k < 4; k++){
    int nn = dir ? (n + 3 - k) : (n - 3 + k);
    if (nn >= 0 && nn < Nn){
      f16x8 v = *(const f16x8*)(base + (size_t)nn * 1024);
      #pragma unroll
      for (int i = 0; i < 8; i++) acc[i] = fmaf(wr[i][k], (float)v[i], acc[i]);
    }
  }
  f16x8 o;
  #pragma unroll
  for (int i = 0; i < 8; i++){ float a = acc[i]; o[i] = (f16)(a * sigm(a)); }
  *(f16x8*)(xi16 + (size_t)idx * 8) = o;
}

// ---------------- selective scan: dt precomputed; y overwrites dt in place ----------------
__global__ __launch_bounds__(256, 2) void scan4_kernel(
    const float* __restrict__ dbc,
    f16* dty,                              // dt in / y out (same buffer, NOT restrict)
    const f16* __restrict__ xi,
    const float* __restrict__ A_log, const float* __restrict__ Dp, int dir)
{
  int tid  = blockIdx.x * 256 + threadIdx.x;
  int g    = tid & 3;
  int chain= tid >> 2;
  int d    = chain & 1023;
  int b    = chain >> 10;
  float4 alog = *(const float4*)(A_log + (size_t)d * 16 + (g << 2));
  float Aj[4] = { -__expf(alog.x), -__expf(alog.y), -__expf(alog.z), -__expf(alog.w) };
  float Dpv  = Dp[d];

  const int stp = dir ? -1 : 1;
  const ptrdiff_t sBC = (ptrdiff_t)stp * 64;
  const ptrdiff_t sX  = (ptrdiff_t)stp * 1024;
  size_t tok0 = (size_t)b * Nn + (dir ? Nn - 1 : 0);
  const float* lB  = dbc + tok0 * 64 + 32 + (g << 2);
  const float* lC  = lB + 16;
  const f16*   lXi = xi  + tok0 * 1024 + d;
  const f16*   lDt = dty + tok0 * 1024 + d;
  f16*         pY  = dty + tok0 * 1024 + d;

  float h[4] = {0.f, 0.f, 0.f, 0.f};
  float  dA_[PF], dB_[PF], xA[PF], xB[PF];
  float4 BA[PF],  BB[PF],  CA[PF], CB[PF];

  auto loadblk = [&](float* dtF, float4* BF, float4* CF, float* xF){
    #pragma unroll
    for (int s = 0; s < PF; s++){
      dtF[s] = (float)lDt[s * sX];
      BF[s]  = *(const float4*)(lB + s * sBC);
      CF[s]  = *(const float4*)(lC + s * sBC);
      xF[s]  = (float)lXi[s * sX];
    }
    lDt += PF * sX; lB += PF * sBC; lC += PF * sBC; lXi += PF * sX;
  };

  auto step = [&](float dt, const float4& Bv, const float4& Cv, float xv){
    float dtx = dt * xv;
    float Br[4] = {Bv.x, Bv.y, Bv.z, Bv.w};
    float Cr[4] = {Cv.x, Cv.y, Cv.z, Cv.w};
    float yv = 0.f;
    #pragma unroll
    for (int j = 0; j < 4; j++){
      float dA = __expf(dt * Aj[j]);
      h[j] = fmaf(dA, h[j], dtx * Br[j]);
      yv = fmaf(h[j], Cr[j], yv);
    }
    yv += __shfl_xor(yv, 1);
    yv += __shfl_xor(yv, 2);
    if (g == 0) *pY = (f16)(yv + xv * Dpv);
    pY += sX;
  };

  loadblk(dA_, BA, CA, xA);          // tokens [0, PF)
  int t = 0;
  for (; t + 3 * PF <= Nn; t += 2 * PF){
    loadblk(dB_, BB, CB, xB);        // loads [t+PF, t+2PF)  (before stores of [t, t+PF))
    asm volatile("" ::: "memory");
    #pragma unroll
    for (int s = 0; s < PF; s++) step(dA_[s], BA[s], CA[s], xA[s]);
    loadblk(dA_, BA, CA, xA);        // loads [t+2PF, t+3PF)
    asm volatile("" ::: "memory");
    #pragma unroll
    for (int s = 0; s < PF; s++) step(dB_[s], BB[s], CB[s], xB[s]);
  }
  int rem = Nn - t;                  // in [PF, 3PF)
  #pragma unroll
  for (int s = 0; s < PF; s++)
    if (s < rem) step(dA_[s], BA[s], CA[s], xA[s]);
  for (int tt = t + PF; tt < Nn; tt++){
    float  dtv = (float)*lDt;
    float4 Bv  = *(const float4*)lB;
    float4 Cv  = *(const float4*)lC;
    float  xv  = (float)*lXi;
    step(dtv, Bv, Cv, xv);
    lDt += sX; lB += sBC; lC += sBC; lXi += sX;
  }
}

// ---------------- (optional add) + LayerNorm; writes f32 e AND f16 e16 ----------------
__global__ __launch_bounds__(256) void add_ln_kernel(
    float* __restrict__ e, const float* __restrict__ add,
    const float* __restrict__ w, const float* __restrict__ bias,
    f16* __restrict__ e16)
{
  int wv = threadIdx.x >> 6, lane = threadIdx.x & 63;
  int tok = blockIdx.x * 4 + wv;
  float* p = e + (size_t)tok * Dm;
  float4 v0 = ((const float4*)p)[lane * 2];
  float4 v1 = ((const float4*)p)[lane * 2 + 1];
  float x[8] = {v0.x, v0.y, v0.z, v0.w, v1.x, v1.y, v1.z, v1.w};
  if (add){
    const float* q = add + (size_t)tok * Dm;
    float4 a0 = ((const float4*)q)[lane * 2];
    float4 a1 = ((const float4*)q)[lane * 2 + 1];
    x[0] += a0.x; x[1] += a0.y; x[2] += a0.z; x[3] += a0.w;
    x[4] += a1.x; x[5] += a1.y; x[6] += a1.z; x[7] += a1.w;
  }
  float s = 0.f;
  #pragma unroll
  for (int i = 0; i < 8; i++) s += x[i];
  #pragma unroll
  for (int off = 32; off; off >>= 1) s += __shfl_xor(s, off);
  float m = s * (1.f / Dm);
  float vv = 0.f;
  #pragma unroll
  for (int i = 0; i < 8; i++){ float dd = x[i] - m; vv += dd * dd; }
  #pragma unroll
  for (int off = 32; off; off >>= 1) vv += __shfl_xor(vv, off);
  float rs = rsqrtf(vv * (1.f / Dm) + EPSf);
  int db = lane * 8;
  float4 w0 = *(const float4*)(w + db),    w1 = *(const float4*)(w + db + 4);
  float4 b0 = *(const float4*)(bias + db), b1 = *(const float4*)(bias + db + 4);
  float wr[8] = {w0.x, w0.y, w0.z, w0.w, w1.x, w1.y, w1.z, w1.w};
  float br[8] = {b0.x, b0.y, b0.z, b0.w, b1.x, b1.y, b1.z, b1.w};
  float o[8];
  #pragma unroll
  for (int i = 0; i < 8; i++) o[i] = (x[i] - m) * rs * wr[i] + br[i];
  ((float4*)p)[lane * 2]     = make_float4(o[0], o[1], o[2], o[3]);
  ((float4*)p)[lane * 2 + 1] = make_float4(o[4], o[5], o[6], o[7]);
  f16x8 hv;
  #pragma unroll
  for (int i = 0; i < 8; i++) hv[i] = (f16)o[i];
  *(f16x8*)(e16 + (size_t)tok * Dm + db) = hv;
}

// ---------------- de-normalize + transpose to (B, FUT, N) ----------------
__global__ __launch_bounds__(256) void final_kernel(
    const float* __restrict__ dec, const float* __restrict__ meanb,
    const float* __restrict__ stdb, const float* __restrict__ rw,
    const float* __restrict__ rb, float* __restrict__ out)
{
  int idx = blockIdx.x * 256 + threadIdx.x;
  if (idx >= Bb * FUTc * Nn) return;
  int n  = idx % Nn;
  int bf = idx / Nn;
  int f  = bf % FUTc;
  int b  = bf / FUTc;
  int tok = b * Nn + n;
  float v = dec[(size_t)tok * FUTc + f];
  out[idx] = (v - rb[n]) / (rw[n] + 1e-10f) * stdb[tok] + meanb[tok];
}

extern "C" void kernel_launch(void* const* d_in, const int* in_sizes, int n_in,
                              void* d_out, int out_size, void* d_ws, size_t ws_size,
                              hipStream_t stream)
{
  const float* x_hist    = (const float*)d_in[0];
  const float* revin_w   = (const float*)d_in[1];
  const float* revin_b   = (const float*)d_in[2];
  const float* embed_w   = (const float*)d_in[3];
  const float* embed_b   = (const float*)d_in[4];
  const float* in_proj_w = (const float*)d_in[5];
  const float* conv_w    = (const float*)d_in[6];
  const float* conv_b    = (const float*)d_in[7];
  const float* x_proj_w  = (const float*)d_in[8];
  const float* dt_proj_w = (const float*)d_in[9];
  const float* dt_proj_b = (const float*)d_in[10];
  const float* A_log     = (const float*)d_in[11];
  const float* Dp        = (const float*)d_in[12];
  const float* out_proj_w= (const float*)d_in[13];
  const float* conv1_w   = (const float*)d_in[14];
  const float* conv1_b   = (const float*)d_in[15];
  const float* conv2_w   = (const float*)d_in[16];
  const float* conv2_b   = (const float*)d_in[17];
  const float* norm1_w   = (const float*)d_in[18];
  const float* norm1_b   = (const float*)d_in[19];
  const float* norm2_w   = (const float*)d_in[20];
  const float* norm2_b   = (const float*)d_in[21];
  const float* normf_w   = (const float*)d_in[22];
  const float* normf_b   = (const float*)d_in[23];
  const float* proj_w    = (const float*)d_in[24];
  const float* proj_b    = (const float*)d_in[25];

  // ---- workspace layout (~224 MB; known ws >= 226 MB) ----
  float* ws    = (float*)d_ws;
  float* meanb = ws;                                    // TT f32
  float* stdb  = meanb + TT;                            // TT f32
  float* e     = stdb + TT;                             // TT*512 f32
  f16*   e16   = (f16*)(e + (size_t)TT * Dm);           // TT*512 f16
  f16*   x16   = e16 + (size_t)TT * Dm;                 // TT*1024 f16 (conv in; dt; y)
  f16*   xi16  = x16 + (size_t)TT * Di;                 // TT*1024 f16 (conv out / scan in)
  float* dbc   = (float*)(xi16 + (size_t)TT * Di);      // TT*64 f32
  f16*   dbc16 = (f16*)(dbc + (size_t)TT * 64);         // TT*64 f16
  f16*   ipw16 = dbc16 + (size_t)TT * 64;               // 4*2048*512
  f16*   opw16 = ipw16 + (size_t)4 * 2048 * Dm;         // 4*512*1024
  f16*   c1w16 = opw16 + (size_t)4 * Dm * Di;           // 2*512*512
  f16*   c2w16 = c1w16 + (size_t)2 * Dm * Dm;           // 2*512*512
  f16*   xpw16 = c2w16 + (size_t)2 * Dm * Dm;           // 4*64*1024
  f16*   dtw16 = xpw16 + (size_t)4 * 64 * Di;           // 4*1024*32
  f16*   emw16 = dtw16 + (size_t)4 * Di * DRr;          // 512*96
  f16*   prw16 = emw16 + (size_t)Dm * Lh;               // 96*512

  // aliases into freed regions
  f16*   xn16  = x16;               // [TT][96] embed staging (pre-loop)
  f16*   h16   = xi16;              // [TT][512] FFN hidden (post-mamba)
  float* ftmp  = (float*)x16;       // [TT][512] f32 conv2 out
  float* dec   = (float*)x16;       // [TT][96] f32 final projection

  dim3 blk(256);
  auto cvt = [&](const float* in, f16* out, size_t n){
    int n4 = (int)(n / 4);
    cvt_kernel<<<(n4 + 255) / 256, blk, 0, stream>>>(in, out, n4);
  };
  cvt(in_proj_w,  ipw16, (size_t)4 * 2048 * Dm);
  cvt(out_proj_w, opw16, (size_t)4 * Dm * Di);
  cvt(conv1_w,    c1w16, (size_t)2 * Dm * Dm);
  cvt(conv2_w,    c2w16, (size_t)2 * Dm * Dm);
  cvt(x_proj_w,   xpw16, (size_t)4 * 64 * Di);
  cvt(dt_proj_w,  dtw16, (size_t)4 * Di * DRr);
  cvt(embed_w,    emw16, (size_t)Dm * Lh);
  cvt(proj_w,     prw16, (size_t)FUTc * Dm);

  stats_kernel<<<(TT + 255) / 256, blk, 0, stream>>>(x_hist, meanb, stdb);
  prep_kernel<<<(Bb * Lh * Nn + 255) / 256, blk, 0, stream>>>(x_hist, meanb, stdb, revin_w, revin_b, xn16);

  const int gy = (TT + 127) / 128;   // 216
  // embed: [TT,96] x [512,96] -> e (f32) + e16
  gemm16_kernel<0,0,1,1><<<dim3(4, gy), blk, 0, stream>>>(
      xn16, Lh, emw16, Lh, embed_b, e, Dm, e16, Dm, Dm, TT);

  for (int l = 0; l < 2; l++){
    for (int dir = 0; dir < 2; dir++){
      int wi = l * 2 + dir;
      const f16* Wx = ipw16 + (size_t)wi * 2048 * Dm;           // rows 0..1023 (x half)
      const f16* Wz = Wx + (size_t)Di * Dm;                     // rows 1024..2047 (z half)
      // in_proj x-half: [TT,512] x [1024,512] -> x16 f16
      gemm16_kernel<0,0,0,1><<<dim3(8, gy), blk, 0, stream>>>(
          e16, Dm, Wx, Dm, nullptr, nullptr, 0, x16, Di, Di, TT);
      // depthwise conv + silu: x16 -> xi16   (x16 dead after this)
      conv_kernel<<<(TT * Di / 8 + 255) / 256, blk, 0, stream>>>(
          x16, conv_w + (size_t)wi * Di * 4, conv_b + (size_t)wi * Di, xi16, dir);
      // x_proj: [TT,1024] x [64,1024] -> dbc f32 + dbc16 f16
      gemm16_kernel<0,0,1,1><<<dim3(1, gy), blk, 0, stream>>>(
          xi16, Di, xpw16 + (size_t)wi * 64 * Di, Di, nullptr,
          dbc, 64, dbc16, 64, 64, TT);
      // dt_proj + softplus: [TT,32(of 64)] x [1024,32] -> dt f16 into x16
      gemm16_kernel<2,0,0,1><<<dim3(8, gy), blk, 0, stream>>>(
          dbc16, 64, dtw16 + (size_t)wi * Di * DRr, DRr, dt_proj_b + (size_t)wi * Di,
          nullptr, 0, x16, Di, Di, TT);
      // scan: dt/B/C/xi in, y overwrites dt (x16)
      scan4_kernel<<<Bb * 16, blk, 0, stream>>>(
          dbc, x16, xi16,
          A_log + (size_t)wi * Di * Ds, Dp + (size_t)wi * Di, dir);
      // gate: y(x16) *= silu(e16 @ Wz^T)   (f16 RMW epilogue)
      gemm16_kernel<3,0,0,1><<<dim3(8, gy), blk, 0, stream>>>(
          e16, Dm, Wz, Dm, nullptr, nullptr, 0, x16, Di, Di, TT);
      // out_proj: [TT,1024] x [512,1024] -> e += (residual accumulate)
      gemm16_kernel<0,1,1,0><<<dim3(4, gy), blk, 0, stream>>>(
          x16, Di, opw16 + (size_t)wi * Dm * Di, Di, nullptr,
          e, Dm, nullptr, 0, Dm, TT);
    }
    // e = LN(e) (mf+mr already accumulated); regenerate e16
    add_ln_kernel<<<TT / 4, blk, 0, stream>>>(e, nullptr, norm1_w + l * Dm, norm1_b + l * Dm, e16);
    // FFN: conv1 relu -> h16 (aliases xi16)
    gemm16_kernel<1,0,0,1><<<dim3(4, gy), blk, 0, stream>>>(
        e16, Dm, c1w16 + (size_t)l * Dm * Dm, Dm, conv1_b + l * Dm,
        nullptr, 0, h16, Dm, Dm, TT);
    // conv2 -> ftmp f32 (aliases x16)
    gemm16_kernel<0,0,1,0><<<dim3(4, gy), blk, 0, stream>>>(
        h16, Dm, c2w16 + (size_t)l * Dm * Dm, Dm, conv2_b + l * Dm,
        ftmp, Dm, nullptr, 0, Dm, TT);
    add_ln_kernel<<<TT / 4, blk, 0, stream>>>(e, ftmp, norm2_w + l * Dm, norm2_b + l * Dm, e16);
  }

  add_ln_kernel<<<TT / 4, blk, 0, stream>>>(e, nullptr, normf_w, normf_b, e16);
  // proj: [TT,512] x [96,512] -> dec f32
  gemm16_kernel<0,0,1,0><<<dim3(1, gy), blk, 0, stream>>>(
      e16, Dm, prw16, Dm, proj_b, dec, FUTc, nullptr, 0, FUTc, TT);
  final_kernel<<<(Bb * FUTc * Nn + 255) / 256, blk, 0, stream>>>(
      dec, meanb, stdb, revin_w, revin_b, (float*)d_out);
}